// Round 1
// baseline (1464.595 us; speedup 1.0000x reference)
//
#include <hip/hip_runtime.h>
#include <hip/hip_bf16.h>
#include <math.h>

#define B_ 2
#define NCLS_ 19
#define N_ 25600
#define C_ 256
#define MAXN_ 1024
#define THRESH_ 100
#define MAXSAMP_ 1024

// ---------------- workspace layout (bytes) ----------------
constexpr size_t OFF_PREDICT = 0;                                   // B*N int
constexpr size_t OFF_PROBC   = OFF_PREDICT + (size_t)B_*N_*4;       // B*N float
constexpr size_t OFF_CNT     = OFF_PROBC + (size_t)B_*N_*4;         // cnt_all[38] + cnt_easy[38]
constexpr size_t OFF_META    = OFF_CNT + 1024;                      // meta[0]=total,[1]=n_view,[2]=n_total
constexpr size_t OFF_PAIRS   = OFF_META + 256;                      // 38 * {qual,h_take,e_take,offset}
constexpr size_t OFF_SELB    = OFF_PAIRS + 1024;
constexpr size_t OFF_SELP    = OFF_SELB + (size_t)MAXN_*4;
constexpr size_t OFF_SELL    = OFF_SELP + (size_t)MAXN_*4;
constexpr size_t OFF_FEAT    = OFF_SELL + (size_t)MAXN_*4;          // MAXN*C float
constexpr size_t OFF_ANCH    = OFF_FEAT + (size_t)MAXN_*C_*4;       // MAXN*C float
constexpr size_t OFF_KEYS    = OFF_ANCH + (size_t)MAXN_*C_*4;       // MAXN*2*C float
constexpr size_t OFF_PAF     = OFF_KEYS + (size_t)MAXN_*2*C_*4;     // MAXN float
constexpr size_t OFF_PAM     = OFF_PAF + (size_t)MAXN_*4;           // MAXN float

__device__ __forceinline__ float bredSum(float v, float* red) {
    int t = threadIdx.x;
    red[t] = v; __syncthreads();
    for (int s = 128; s > 0; s >>= 1) { if (t < s) red[t] += red[t + s]; __syncthreads(); }
    float r = red[0]; __syncthreads();
    return r;
}

// ---------------- 1. softmax / argmax / histograms ----------------
__global__ void k_softmax_predict(const float* __restrict__ seg, const int* __restrict__ gt,
                                  int* __restrict__ predict, float* __restrict__ probc,
                                  int* __restrict__ cnt_all, int* __restrict__ cnt_easy) {
    __shared__ int h_all[B_*NCLS_];
    __shared__ int h_easy[B_*NCLS_];
    int t = threadIdx.x;
    if (t < B_*NCLS_) { h_all[t] = 0; h_easy[t] = 0; }
    __syncthreads();
    int idx = blockIdx.x * blockDim.x + t;
    if (idx < B_*N_) {
        int b = idx / N_, p = idx - b*N_;
        const float* base = seg + (size_t)b*NCLS_*N_ + p;
        float v[NCLS_];
        float mx = base[0]; v[0] = mx; int am = 0;
        for (int k = 1; k < NCLS_; ++k) {
            float x = base[(size_t)k*N_];
            v[k] = x;
            if (x > mx) { mx = x; am = k; }
        }
        float s = 0.f;
        for (int k = 0; k < NCLS_; ++k) s += expf(v[k] - mx);
        int lab = gt[idx];
        float pv = 0.f;
        if (lab >= 0 && lab < NCLS_) {
            pv = expf(v[lab] - mx) / s;
            atomicAdd(&h_all[b*NCLS_ + lab], 1);
            if (am == lab) atomicAdd(&h_easy[b*NCLS_ + lab], 1);
        }
        predict[idx] = am;
        probc[idx] = pv;
    }
    __syncthreads();
    if (t < B_*NCLS_) {
        if (h_all[t])  atomicAdd(&cnt_all[t],  h_all[t]);
        if (h_easy[t]) atomicAdd(&cnt_easy[t], h_easy[t]);
    }
}

// ---------------- 2. mining plan (single thread) ----------------
__global__ void k_plan(const int* __restrict__ cnt_all, const int* __restrict__ cnt_easy,
                       int* __restrict__ meta, int* __restrict__ pairs) {
    if (threadIdx.x != 0 || blockIdx.x != 0) return;
    int total = 0;
    for (int i = 0; i < B_*NCLS_; ++i) if (cnt_all[i] > THRESH_) total++;
    meta[0] = total;
    int n_view = 0;
    if (total > 0) { n_view = MAXSAMP_ / total; if (n_view > THRESH_) n_view = THRESH_; }
    meta[1] = n_view;
    int off = 0;
    for (int i = 0; i < B_*NCLS_; ++i) {
        int q = (cnt_all[i] > THRESH_) ? 1 : 0;
        int h_take = 0, e_take = 0;
        if (q) {
            int ne = cnt_easy[i];
            int nh = cnt_all[i] - ne;
            int nhk, nek;
            bool hb = 2*nh >= n_view, eb = 2*ne >= n_view;
            if (hb && eb)      { nhk = n_view/2; nek = n_view - nhk; }
            else if (hb)       { nek = ne;       nhk = n_view - nek; }
            else if (eb)       { nhk = nh;       nek = n_view - nhk; }
            else               { nhk = nh;       nek = ne; }
            h_take = nhk < nh ? nhk : nh;
            e_take = nek < ne ? nek : ne;
        }
        pairs[4*i+0] = q; pairs[4*i+1] = h_take; pairs[4*i+2] = e_take; pairs[4*i+3] = off;
        off += h_take + e_take;
    }
    meta[2] = off;
}

// ---------------- 3. top-k selection per (batch,class) ----------------
__global__ void k_select(const int* __restrict__ gt, const int* __restrict__ predict,
                         const float* __restrict__ probc, const int* __restrict__ pairs,
                         int* __restrict__ sel_b, int* __restrict__ sel_p, int* __restrict__ sel_l) {
    int slot = blockIdx.x;
    if (!pairs[4*slot]) return;
    int i = slot / NCLS_, c = slot - i*NCLS_;
    int h_take = pairs[4*slot+1], e_take = pairs[4*slot+2], off = pairs[4*slot+3];
    const int*   lab = gt      + (size_t)i*N_;
    const int*   prd = predict + (size_t)i*N_;
    const float* pb  = probc   + (size_t)i*N_;
    __shared__ float s_val[256];
    __shared__ int   s_idx[256];
    int t = threadIdx.x;

    // hard: descending prob, ties by ascending pixel index
    float prev_v = INFINITY; int prev_i = -1;
    for (int it = 0; it < h_take; ++it) {
        float bv = -INFINITY; int bi = -1;
        for (int p = t; p < N_; p += 256) {
            if (lab[p] == c && prd[p] != c) {
                float v = pb[p];
                bool valid = (v < prev_v) || (v == prev_v && p > prev_i);
                if (valid && (v > bv || (v == bv && (bi < 0 || p < bi)))) { bv = v; bi = p; }
            }
        }
        s_val[t] = bv; s_idx[t] = bi; __syncthreads();
        for (int s = 128; s > 0; s >>= 1) {
            if (t < s) {
                float ov = s_val[t+s]; int oi = s_idx[t+s];
                if (oi >= 0 && (s_idx[t] < 0 || ov > s_val[t] || (ov == s_val[t] && oi < s_idx[t]))) {
                    s_val[t] = ov; s_idx[t] = oi;
                }
            }
            __syncthreads();
        }
        prev_v = s_val[0]; prev_i = s_idx[0];
        __syncthreads();
        if (t == 0) { sel_b[off+it] = i; sel_p[off+it] = prev_i; sel_l[off+it] = c; }
    }
    __syncthreads();

    // easy: ascending prob, ties by ascending pixel index
    prev_v = -INFINITY; prev_i = -1;
    for (int it = 0; it < e_take; ++it) {
        float bv = INFINITY; int bi = -1;
        for (int p = t; p < N_; p += 256) {
            if (lab[p] == c && prd[p] == c) {
                float v = pb[p];
                bool valid = (v > prev_v) || (v == prev_v && p > prev_i);
                if (valid && (v < bv || (v == bv && (bi < 0 || p < bi)))) { bv = v; bi = p; }
            }
        }
        s_val[t] = bv; s_idx[t] = bi; __syncthreads();
        for (int s = 128; s > 0; s >>= 1) {
            if (t < s) {
                float ov = s_val[t+s]; int oi = s_idx[t+s];
                if (oi >= 0 && (s_idx[t] < 0 || ov < s_val[t] || (ov == s_val[t] && oi < s_idx[t]))) {
                    s_val[t] = ov; s_idx[t] = oi;
                }
            }
            __syncthreads();
        }
        prev_v = s_val[0]; prev_i = s_idx[0];
        __syncthreads();
        if (t == 0) { sel_b[off+h_take+it] = i; sel_p[off+h_take+it] = prev_i; sel_l[off+h_take+it] = c; }
    }
}

// ---------------- 4. gather + l2-normalize selected vectors ----------------
__global__ void k_gather(const float* __restrict__ pf, const float* __restrict__ pm,
                         const int* __restrict__ meta, const int* __restrict__ sel_b,
                         const int* __restrict__ sel_p,
                         float* __restrict__ sfeat, float* __restrict__ sanch, float* __restrict__ skeys) {
    __shared__ float red[256];
    int s = blockIdx.x;
    if (s >= meta[2]) return;
    int b = sel_b[s], p = sel_p[s];
    int t = threadIdx.x;  // == channel (blockDim == C_)
    {
        float x = pf[((size_t)(b*C_ + t))*N_ + p];
        float ss = bredSum(x*x, red);
        sfeat[(size_t)s*C_ + t] = x / fmaxf(sqrtf(ss), 1e-12f);
    }
    {
        float x = pm[((size_t)((2*B_ + b)*C_ + t))*N_ + p];
        float ss = bredSum(x*x, red);
        sanch[(size_t)s*C_ + t] = x / fmaxf(sqrtf(ss), 1e-12f);
    }
    for (int j = 0; j < 2; ++j) {
        float x = pm[((size_t)((j*B_ + b)*C_ + t))*N_ + p];
        float ss = bredSum(x*x, red);
        skeys[((size_t)(2*s + j))*C_ + t] = x / fmaxf(sqrtf(ss), 1e-12f);
    }
}

// ---------------- 5. feature-contrastive per-anchor ----------------
__global__ void k_feat_rows(const int* __restrict__ meta, const float* __restrict__ sfeat,
                            const int* __restrict__ sel_l, float* __restrict__ paf) {
    __shared__ float fa[C_];
    __shared__ float row[MAXN_];
    __shared__ int   sl[MAXN_];
    __shared__ float red[256];
    int n = meta[2];
    int a = blockIdx.x;
    if (a >= n) return;
    int t = threadIdx.x;
    fa[t] = sfeat[(size_t)a*C_ + t];
    for (int b0 = t; b0 < n; b0 += 256) sl[b0] = sel_l[b0];
    __syncthreads();
    for (int b0 = t; b0 < n; b0 += 256) {
        const float* fb = sfeat + (size_t)b0*C_;
        float d = 0.f;
        #pragma unroll 8
        for (int ch = 0; ch < C_; ++ch) d += fa[ch]*fb[ch];
        row[b0] = d / 0.1f;
    }
    __syncthreads();
    float mx = -INFINITY;
    for (int b0 = t; b0 < n; b0 += 256) mx = fmaxf(mx, row[b0]);
    red[t] = mx; __syncthreads();
    for (int s = 128; s > 0; s >>= 1) { if (t < s) red[t] = fmaxf(red[t], red[t+s]); __syncthreads(); }
    mx = red[0]; __syncthreads();
    int la = sl[a];
    float se = 0.f, sp = 0.f, np = 0.f;
    for (int b0 = t; b0 < n; b0 += 256) {
        float l = row[b0] - mx;
        if (b0 != a) {
            se += expf(l);
            if (sl[b0] == la) { sp += l; np += 1.f; }
        }
    }
    se = bredSum(se, red);
    sp = bredSum(sp, red);
    np = bredSum(np, red);
    if (t == 0) {
        float lg = logf(se + 1e-16f);
        paf[a] = (sp - np*lg) / (np + 1e-16f);
    }
}

// ---------------- 6. mask-contrastive per-anchor ----------------
__global__ void k_mask_rows(const int* __restrict__ meta, const float* __restrict__ sanch,
                            const float* __restrict__ skeys, const int* __restrict__ sel_l,
                            float* __restrict__ pam) {
    __shared__ float aa[C_];
    __shared__ float row[3*MAXN_];
    __shared__ int   sl[MAXN_];
    __shared__ float red[256];
    int n = meta[2];
    int a = blockIdx.x;
    if (a >= n) return;
    int t = threadIdx.x;
    aa[t] = sanch[(size_t)a*C_ + t];
    for (int b0 = t; b0 < n; b0 += 256) sl[b0] = sel_l[b0];
    __syncthreads();
    int M = 3*n;
    for (int m0 = t; m0 < M; m0 += 256) {
        const float* v = (m0 < n) ? (sanch + (size_t)m0*C_) : (skeys + (size_t)(m0 - n)*C_);
        float d = 0.f;
        #pragma unroll 8
        for (int ch = 0; ch < C_; ++ch) d += aa[ch]*v[ch];
        row[m0] = d / 0.1f;
    }
    __syncthreads();
    float mx = -INFINITY;
    for (int m0 = t; m0 < M; m0 += 256) mx = fmaxf(mx, row[m0]);
    red[t] = mx; __syncthreads();
    for (int s = 128; s > 0; s >>= 1) { if (t < s) red[t] = fmaxf(red[t], red[t+s]); __syncthreads(); }
    mx = red[0]; __syncthreads();
    int la = sl[a];
    float dn = 0.f, st = 0.f, nt = 0.f;
    for (int m0 = t; m0 < M; m0 += 256) {
        float l = row[m0] - mx;
        bool tot;
        if (m0 < n) tot = (sl[m0] == la) && (m0 != a);
        else { int q = m0 - n; int qm = q < n ? q : q - n; tot = (sl[qm] == la); }
        if (tot) { st += l; nt += 1.f; }
        else dn += expf(l);
    }
    dn = bredSum(dn, red);
    st = bredSum(st, red);
    nt = bredSum(nt, red);
    if (t == 0) {
        float lg = logf(dn + 1e-16f);
        pam[a] = (st - nt*lg) / (nt + 1e-16f);
    }
}

// ---------------- 7. finalize ----------------
__global__ void k_final(const int* __restrict__ meta, const float* __restrict__ paf,
                        const float* __restrict__ pam, float* __restrict__ out) {
    __shared__ float red[256];
    int n = meta[2];
    int total = meta[0];
    int t = threadIdx.x;
    float sf = 0.f, sm = 0.f;
    for (int a = t; a < n; a += 256) { sf += paf[a]; sm += pam[a]; }
    sf = bredSum(sf, red);
    sm = bredSum(sm, red);
    if (t == 0) {
        if (total == 0 || n == 0) { out[0] = 0.f; out[1] = 0.f; }
        else {
            float scale = (float)(-(0.1/0.07));
            out[0] = scale * (sf / (float)n) * 0.1f;   // FEAT_W
            out[1] = scale * (sm / (float)n) * 0.1f;   // MASK_W
        }
    }
}

extern "C" void kernel_launch(void* const* d_in, const int* in_sizes, int n_in,
                              void* d_out, int out_size, void* d_ws, size_t ws_size,
                              hipStream_t stream) {
    const float* pf  = (const float*)d_in[0];   // proj_feats (B,C,H,W)
    const float* seg = (const float*)d_in[1];   // seg_logits (B,19,H,W)
    const int*   gt  = (const int*)d_in[2];     // groundtruth (B,1,H,W)
    const float* pm  = (const float*)d_in[3];   // proj_masks (3,B,256,H,W)
    float* out = (float*)d_out;
    char* ws = (char*)d_ws;

    int*   predict  = (int*)(ws + OFF_PREDICT);
    float* probc    = (float*)(ws + OFF_PROBC);
    int*   cnt_all  = (int*)(ws + OFF_CNT);
    int*   cnt_easy = cnt_all + B_*NCLS_;
    int*   meta     = (int*)(ws + OFF_META);
    int*   pairs    = (int*)(ws + OFF_PAIRS);
    int*   sel_b    = (int*)(ws + OFF_SELB);
    int*   sel_p    = (int*)(ws + OFF_SELP);
    int*   sel_l    = (int*)(ws + OFF_SELL);
    float* sfeat    = (float*)(ws + OFF_FEAT);
    float* sanch    = (float*)(ws + OFF_ANCH);
    float* skeys    = (float*)(ws + OFF_KEYS);
    float* paf      = (float*)(ws + OFF_PAF);
    float* pam      = (float*)(ws + OFF_PAM);

    hipMemsetAsync(ws + OFF_CNT, 0, 2*B_*NCLS_*sizeof(int), stream);

    k_softmax_predict<<<(B_*N_ + 255)/256, 256, 0, stream>>>(seg, gt, predict, probc, cnt_all, cnt_easy);
    k_plan<<<1, 1, 0, stream>>>(cnt_all, cnt_easy, meta, pairs);
    k_select<<<B_*NCLS_, 256, 0, stream>>>(gt, predict, probc, pairs, sel_b, sel_p, sel_l);
    k_gather<<<MAXN_, 256, 0, stream>>>(pf, pm, meta, sel_b, sel_p, sfeat, sanch, skeys);
    k_feat_rows<<<MAXN_, 256, 0, stream>>>(meta, sfeat, sel_l, paf);
    k_mask_rows<<<MAXN_, 256, 0, stream>>>(meta, sanch, skeys, sel_l, pam);
    k_final<<<1, 256, 0, stream>>>(meta, paf, pam, out);
}

// Round 2
// 658.610 us; speedup vs baseline: 2.2238x; 2.2238x over previous
//
#include <hip/hip_runtime.h>
#include <hip/hip_bf16.h>
#include <math.h>

#define B_ 2
#define NCLS_ 19
#define N_ 25600
#define C_ 256
#define MAXN_ 1024
#define THRESH_ 100
#define MAXSAMP_ 1024
#define NLIST_ (B_*NCLS_*2)
#define CAP_ 6144

// ---------------- workspace layout (bytes) ----------------
constexpr size_t OFF_PREDICT = 0;                                   // B*N int
constexpr size_t OFF_PROBC   = OFF_PREDICT + (size_t)B_*N_*4;       // B*N float
constexpr size_t OFF_CNT     = OFF_PROBC + (size_t)B_*N_*4;         // cnt_all[38] + cnt_easy[38]
constexpr size_t OFF_META    = OFF_CNT + 1024;                      // meta[0]=total,[1]=n_view,[2]=n_total
constexpr size_t OFF_PAIRS   = OFF_META + 256;                      // 38 * {qual,h_take,e_take,offset}
constexpr size_t OFF_SELB    = OFF_PAIRS + 1024;
constexpr size_t OFF_SELP    = OFF_SELB + (size_t)MAXN_*4;
constexpr size_t OFF_SELL    = OFF_SELP + (size_t)MAXN_*4;
constexpr size_t OFF_FEAT    = OFF_SELL + (size_t)MAXN_*4;          // MAXN*C float (aliased by CAND pre-gather)
constexpr size_t OFF_ANCH    = OFF_FEAT + (size_t)MAXN_*C_*4;       // MAXN*C float
constexpr size_t OFF_KEYS    = OFF_ANCH + (size_t)MAXN_*C_*4;       // MAXN*2*C float
constexpr size_t OFF_PAF     = OFF_KEYS + (size_t)MAXN_*2*C_*4;     // MAXN float
constexpr size_t OFF_PAM     = OFF_PAF + (size_t)MAXN_*4;           // MAXN float
constexpr size_t OFF_LBASE   = OFF_PAM + (size_t)MAXN_*4;           // NLIST ints
constexpr size_t OFF_CURS    = OFF_LBASE + 512;                     // NLIST ints
// candidate keys alias the FEAT region (B*N u64 = 400 KB <= 1 MB; dead once gather runs)
constexpr size_t OFF_CAND    = OFF_FEAT;

__device__ __forceinline__ float bredSum(float v, float* red) {
    int t = threadIdx.x;
    red[t] = v; __syncthreads();
    for (int s = 128; s > 0; s >>= 1) { if (t < s) red[t] += red[t + s]; __syncthreads(); }
    float r = red[0]; __syncthreads();
    return r;
}

// ---------------- 1. softmax / argmax / histograms ----------------
__global__ void k_softmax_predict(const float* __restrict__ seg, const int* __restrict__ gt,
                                  int* __restrict__ predict, float* __restrict__ probc,
                                  int* __restrict__ cnt_all, int* __restrict__ cnt_easy) {
    __shared__ int h_all[B_*NCLS_];
    __shared__ int h_easy[B_*NCLS_];
    int t = threadIdx.x;
    if (t < B_*NCLS_) { h_all[t] = 0; h_easy[t] = 0; }
    __syncthreads();
    int idx = blockIdx.x * blockDim.x + t;
    if (idx < B_*N_) {
        int b = idx / N_, p = idx - b*N_;
        const float* base = seg + (size_t)b*NCLS_*N_ + p;
        float v[NCLS_];
        float mx = base[0]; v[0] = mx; int am = 0;
        for (int k = 1; k < NCLS_; ++k) {
            float x = base[(size_t)k*N_];
            v[k] = x;
            if (x > mx) { mx = x; am = k; }
        }
        float s = 0.f;
        for (int k = 0; k < NCLS_; ++k) s += expf(v[k] - mx);
        int lab = gt[idx];
        float pv = 0.f;
        if (lab >= 0 && lab < NCLS_) {
            pv = expf(v[lab] - mx) / s;
            atomicAdd(&h_all[b*NCLS_ + lab], 1);
            if (am == lab) atomicAdd(&h_easy[b*NCLS_ + lab], 1);
        }
        predict[idx] = am;
        probc[idx] = pv;
    }
    __syncthreads();
    if (t < B_*NCLS_) {
        if (h_all[t])  atomicAdd(&cnt_all[t],  h_all[t]);
        if (h_easy[t]) atomicAdd(&cnt_easy[t], h_easy[t]);
    }
}

// ---------------- 2. mining plan (single thread) ----------------
__global__ void k_plan(const int* __restrict__ cnt_all, const int* __restrict__ cnt_easy,
                       int* __restrict__ meta, int* __restrict__ pairs,
                       int* __restrict__ lbase, int* __restrict__ cursor) {
    if (threadIdx.x != 0 || blockIdx.x != 0) return;
    int total = 0;
    for (int i = 0; i < B_*NCLS_; ++i) if (cnt_all[i] > THRESH_) total++;
    meta[0] = total;
    int n_view = 0;
    if (total > 0) { n_view = MAXSAMP_ / total; if (n_view > THRESH_) n_view = THRESH_; }
    meta[1] = n_view;
    int off = 0;
    for (int i = 0; i < B_*NCLS_; ++i) {
        int q = (cnt_all[i] > THRESH_) ? 1 : 0;
        int h_take = 0, e_take = 0;
        if (q) {
            int ne = cnt_easy[i];
            int nh = cnt_all[i] - ne;
            int nhk, nek;
            bool hb = 2*nh >= n_view, eb = 2*ne >= n_view;
            if (hb && eb)      { nhk = n_view/2; nek = n_view - nhk; }
            else if (hb)       { nek = ne;       nhk = n_view - nek; }
            else if (eb)       { nhk = nh;       nek = n_view - nhk; }
            else               { nhk = nh;       nek = ne; }
            h_take = nhk < nh ? nhk : nh;
            e_take = nek < ne ? nek : ne;
        }
        pairs[4*i+0] = q; pairs[4*i+1] = h_take; pairs[4*i+2] = e_take; pairs[4*i+3] = off;
        off += h_take + e_take;
    }
    meta[2] = off;
    // candidate-list bases: list L = (b*NCLS+c)*2 + ishard
    int run = 0;
    for (int i = 0; i < B_*NCLS_; ++i) {
        int ne = cnt_easy[i];
        int nh = cnt_all[i] - ne;
        lbase[2*i+0] = run; run += ne;   // easy list
        lbase[2*i+1] = run; run += nh;   // hard list
        cursor[2*i+0] = 0; cursor[2*i+1] = 0;
    }
}

// ---------------- 3a. compact candidates into per-list segments ----------------
__global__ void k_scatter(const int* __restrict__ gt, const int* __restrict__ predict,
                          const float* __restrict__ probc, const int* __restrict__ lbase,
                          int* __restrict__ cursor, unsigned long long* __restrict__ cand) {
    int idx = blockIdx.x * blockDim.x + threadIdx.x;
    if (idx >= B_*N_) return;
    int lab = gt[idx];
    if (lab < 0 || lab >= NCLS_) return;
    int b = idx / N_, p = idx - b*N_;
    int ishard = (predict[idx] != lab) ? 1 : 0;
    int L = (b*NCLS_ + lab)*2 + ishard;
    int pos = atomicAdd(&cursor[L], 1);
    unsigned int pb = __float_as_uint(probc[idx]);
    // hard lists: max-order = (desc prob, asc pixel)  -> complement pixel
    // easy lists: min-order = (asc prob, asc pixel)   -> plain pixel
    unsigned int lo = ishard ? (0xFFFFFFFFu - (unsigned int)p) : (unsigned int)p;
    cand[(size_t)lbase[L] + pos] = ((unsigned long long)pb << 32) | (unsigned long long)lo;
}

// ---------------- 3b. exact ordered top-k per list ----------------
__global__ void k_select2(const int* __restrict__ cnt_all, const int* __restrict__ cnt_easy,
                          const int* __restrict__ pairs, const int* __restrict__ lbase,
                          const unsigned long long* __restrict__ cand,
                          int* __restrict__ sel_b, int* __restrict__ sel_p, int* __restrict__ sel_l) {
    __shared__ unsigned long long s_key[256];
    __shared__ unsigned long long keys[CAP_];
    int bid = blockIdx.x;
    int slot = bid >> 1, ishard = bid & 1;
    if (!pairs[4*slot]) return;
    int h_take = pairs[4*slot+1], e_take = pairs[4*slot+2];
    int take = ishard ? h_take : e_take;
    if (take == 0) return;
    int off = pairs[4*slot+3] + (ishard ? 0 : h_take);
    int ne = cnt_easy[slot];
    int m = ishard ? (cnt_all[slot] - ne) : ne;
    int L = slot*2 + ishard;
    const unsigned long long* g = cand + lbase[L];
    int t = threadIdx.x;
    bool fits = (m <= CAP_);
    if (fits) {
        for (int j = t; j < m; j += 256) keys[j] = g[j];
        __syncthreads();
    }
    int b = slot / NCLS_, c = slot - b*NCLS_;
    unsigned long long prev = ishard ? 0xFFFFFFFFFFFFFFFFull : 0ull;
    for (int it = 0; it < take; ++it) {
        unsigned long long best = ishard ? 0ull : 0xFFFFFFFFFFFFFFFFull;
        if (ishard) {
            for (int j = t; j < m; j += 256) {
                unsigned long long k = fits ? keys[j] : g[j];
                if (k < prev && k > best) best = k;
            }
        } else {
            for (int j = t; j < m; j += 256) {
                unsigned long long k = fits ? keys[j] : g[j];
                if (k > prev && k < best) best = k;
            }
        }
        s_key[t] = best; __syncthreads();
        for (int s = 128; s > 0; s >>= 1) {
            if (t < s) {
                unsigned long long o = s_key[t+s];
                if (ishard ? (o > s_key[t]) : (o < s_key[t])) s_key[t] = o;
            }
            __syncthreads();
        }
        prev = s_key[0]; __syncthreads();
        if (t == 0) {
            unsigned int lo = (unsigned int)(prev & 0xFFFFFFFFull);
            int p = ishard ? (int)(0xFFFFFFFFu - lo) : (int)lo;
            sel_b[off+it] = b; sel_p[off+it] = p; sel_l[off+it] = c;
        }
    }
}

// ---------------- 4. gather + l2-normalize selected vectors ----------------
__global__ void k_gather(const float* __restrict__ pf, const float* __restrict__ pm,
                         const int* __restrict__ meta, const int* __restrict__ sel_b,
                         const int* __restrict__ sel_p,
                         float* __restrict__ sfeat, float* __restrict__ sanch, float* __restrict__ skeys) {
    __shared__ float red[256];
    int s = blockIdx.x;
    if (s >= meta[2]) return;
    int b = sel_b[s], p = sel_p[s];
    int t = threadIdx.x;  // == channel (blockDim == C_)
    {
        float x = pf[((size_t)(b*C_ + t))*N_ + p];
        float ss = bredSum(x*x, red);
        sfeat[(size_t)s*C_ + t] = x / fmaxf(sqrtf(ss), 1e-12f);
    }
    {
        float x = pm[((size_t)((2*B_ + b)*C_ + t))*N_ + p];
        float ss = bredSum(x*x, red);
        sanch[(size_t)s*C_ + t] = x / fmaxf(sqrtf(ss), 1e-12f);
    }
    for (int j = 0; j < 2; ++j) {
        float x = pm[((size_t)((j*B_ + b)*C_ + t))*N_ + p];
        float ss = bredSum(x*x, red);
        skeys[((size_t)(2*s + j))*C_ + t] = x / fmaxf(sqrtf(ss), 1e-12f);
    }
}

// ---------------- 5. feature-contrastive per-anchor ----------------
__global__ void k_feat_rows(const int* __restrict__ meta, const float* __restrict__ sfeat,
                            const int* __restrict__ sel_l, float* __restrict__ paf) {
    __shared__ float fa[C_];
    __shared__ float row[MAXN_];
    __shared__ int   sl[MAXN_];
    __shared__ float red[256];
    int n = meta[2];
    int a = blockIdx.x;
    if (a >= n) return;
    int t = threadIdx.x;
    fa[t] = sfeat[(size_t)a*C_ + t];
    for (int b0 = t; b0 < n; b0 += 256) sl[b0] = sel_l[b0];
    __syncthreads();
    for (int b0 = t; b0 < n; b0 += 256) {
        const float* fb = sfeat + (size_t)b0*C_;
        float d = 0.f;
        #pragma unroll 8
        for (int ch = 0; ch < C_; ++ch) d += fa[ch]*fb[ch];
        row[b0] = d / 0.1f;
    }
    __syncthreads();
    float mx = -INFINITY;
    for (int b0 = t; b0 < n; b0 += 256) mx = fmaxf(mx, row[b0]);
    red[t] = mx; __syncthreads();
    for (int s = 128; s > 0; s >>= 1) { if (t < s) red[t] = fmaxf(red[t], red[t+s]); __syncthreads(); }
    mx = red[0]; __syncthreads();
    int la = sl[a];
    float se = 0.f, sp = 0.f, np = 0.f;
    for (int b0 = t; b0 < n; b0 += 256) {
        float l = row[b0] - mx;
        if (b0 != a) {
            se += expf(l);
            if (sl[b0] == la) { sp += l; np += 1.f; }
        }
    }
    se = bredSum(se, red);
    sp = bredSum(sp, red);
    np = bredSum(np, red);
    if (t == 0) {
        float lg = logf(se + 1e-16f);
        paf[a] = (sp - np*lg) / (np + 1e-16f);
    }
}

// ---------------- 6. mask-contrastive per-anchor ----------------
__global__ void k_mask_rows(const int* __restrict__ meta, const float* __restrict__ sanch,
                            const float* __restrict__ skeys, const int* __restrict__ sel_l,
                            float* __restrict__ pam) {
    __shared__ float aa[C_];
    __shared__ float row[3*MAXN_];
    __shared__ int   sl[MAXN_];
    __shared__ float red[256];
    int n = meta[2];
    int a = blockIdx.x;
    if (a >= n) return;
    int t = threadIdx.x;
    aa[t] = sanch[(size_t)a*C_ + t];
    for (int b0 = t; b0 < n; b0 += 256) sl[b0] = sel_l[b0];
    __syncthreads();
    int M = 3*n;
    for (int m0 = t; m0 < M; m0 += 256) {
        const float* v = (m0 < n) ? (sanch + (size_t)m0*C_) : (skeys + (size_t)(m0 - n)*C_);
        float d = 0.f;
        #pragma unroll 8
        for (int ch = 0; ch < C_; ++ch) d += aa[ch]*v[ch];
        row[m0] = d / 0.1f;
    }
    __syncthreads();
    float mx = -INFINITY;
    for (int m0 = t; m0 < M; m0 += 256) mx = fmaxf(mx, row[m0]);
    red[t] = mx; __syncthreads();
    for (int s = 128; s > 0; s >>= 1) { if (t < s) red[t] = fmaxf(red[t], red[t+s]); __syncthreads(); }
    mx = red[0]; __syncthreads();
    int la = sl[a];
    float dn = 0.f, st = 0.f, nt = 0.f;
    for (int m0 = t; m0 < M; m0 += 256) {
        float l = row[m0] - mx;
        bool tot;
        if (m0 < n) tot = (sl[m0] == la) && (m0 != a);
        else { int q = m0 - n; int qm = q < n ? q : q - n; tot = (sl[qm] == la); }
        if (tot) { st += l; nt += 1.f; }
        else dn += expf(l);
    }
    dn = bredSum(dn, red);
    st = bredSum(st, red);
    nt = bredSum(nt, red);
    if (t == 0) {
        float lg = logf(dn + 1e-16f);
        pam[a] = (st - nt*lg) / (nt + 1e-16f);
    }
}

// ---------------- 7. finalize ----------------
__global__ void k_final(const int* __restrict__ meta, const float* __restrict__ paf,
                        const float* __restrict__ pam, float* __restrict__ out) {
    __shared__ float red[256];
    int n = meta[2];
    int total = meta[0];
    int t = threadIdx.x;
    float sf = 0.f, sm = 0.f;
    for (int a = t; a < n; a += 256) { sf += paf[a]; sm += pam[a]; }
    sf = bredSum(sf, red);
    sm = bredSum(sm, red);
    if (t == 0) {
        if (total == 0 || n == 0) { out[0] = 0.f; out[1] = 0.f; }
        else {
            float scale = (float)(-(0.1/0.07));
            out[0] = scale * (sf / (float)n) * 0.1f;   // FEAT_W
            out[1] = scale * (sm / (float)n) * 0.1f;   // MASK_W
        }
    }
}

extern "C" void kernel_launch(void* const* d_in, const int* in_sizes, int n_in,
                              void* d_out, int out_size, void* d_ws, size_t ws_size,
                              hipStream_t stream) {
    const float* pf  = (const float*)d_in[0];   // proj_feats (B,C,H,W)
    const float* seg = (const float*)d_in[1];   // seg_logits (B,19,H,W)
    const int*   gt  = (const int*)d_in[2];     // groundtruth (B,1,H,W)
    const float* pm  = (const float*)d_in[3];   // proj_masks (3,B,256,H,W)
    float* out = (float*)d_out;
    char* ws = (char*)d_ws;

    int*   predict  = (int*)(ws + OFF_PREDICT);
    float* probc    = (float*)(ws + OFF_PROBC);
    int*   cnt_all  = (int*)(ws + OFF_CNT);
    int*   cnt_easy = cnt_all + B_*NCLS_;
    int*   meta     = (int*)(ws + OFF_META);
    int*   pairs    = (int*)(ws + OFF_PAIRS);
    int*   sel_b    = (int*)(ws + OFF_SELB);
    int*   sel_p    = (int*)(ws + OFF_SELP);
    int*   sel_l    = (int*)(ws + OFF_SELL);
    float* sfeat    = (float*)(ws + OFF_FEAT);
    float* sanch    = (float*)(ws + OFF_ANCH);
    float* skeys    = (float*)(ws + OFF_KEYS);
    float* paf      = (float*)(ws + OFF_PAF);
    float* pam      = (float*)(ws + OFF_PAM);
    int*   lbase    = (int*)(ws + OFF_LBASE);
    int*   cursor   = (int*)(ws + OFF_CURS);
    unsigned long long* cand = (unsigned long long*)(ws + OFF_CAND);

    hipMemsetAsync(ws + OFF_CNT, 0, 2*B_*NCLS_*sizeof(int), stream);

    k_softmax_predict<<<(B_*N_ + 255)/256, 256, 0, stream>>>(seg, gt, predict, probc, cnt_all, cnt_easy);
    k_plan<<<1, 1, 0, stream>>>(cnt_all, cnt_easy, meta, pairs, lbase, cursor);
    k_scatter<<<(B_*N_ + 255)/256, 256, 0, stream>>>(gt, predict, probc, lbase, cursor, cand);
    k_select2<<<NLIST_, 256, 0, stream>>>(cnt_all, cnt_easy, pairs, lbase, cand, sel_b, sel_p, sel_l);
    k_gather<<<MAXN_, 256, 0, stream>>>(pf, pm, meta, sel_b, sel_p, sfeat, sanch, skeys);
    k_feat_rows<<<MAXN_, 256, 0, stream>>>(meta, sfeat, sel_l, paf);
    k_mask_rows<<<MAXN_, 256, 0, stream>>>(meta, sanch, skeys, sel_l, pam);
    k_final<<<1, 256, 0, stream>>>(meta, paf, pam, out);
}

// Round 3
// 389.741 us; speedup vs baseline: 3.7579x; 1.6899x over previous
//
#include <hip/hip_runtime.h>
#include <hip/hip_bf16.h>
#include <math.h>

#define B_ 2
#define NCLS_ 19
#define N_ 25600
#define C_ 256
#define MAXN_ 1024
#define THRESH_ 100
#define MAXSAMP_ 1024
#define NLIST_ (B_*NCLS_*2)
#define CAP_ 6144
#define NRF_ 8     // feat key ranges (MAXN/128)
#define NRM_ 24    // mask key ranges (3*MAXN/128)

// ---------------- workspace layout (bytes) ----------------
constexpr size_t OFF_PREDICT = 0;                                   // B*N int
constexpr size_t OFF_PROBC   = OFF_PREDICT + (size_t)B_*N_*4;       // B*N float
constexpr size_t OFF_CNT     = OFF_PROBC + (size_t)B_*N_*4;
constexpr size_t OFF_META    = OFF_CNT + 1024;
constexpr size_t OFF_PAIRS   = OFF_META + 256;
constexpr size_t OFF_SELB    = OFF_PAIRS + 1024;
constexpr size_t OFF_SELP    = OFF_SELB + (size_t)MAXN_*4;
constexpr size_t OFF_SELL    = OFF_SELP + (size_t)MAXN_*4;
constexpr size_t OFF_FEAT    = OFF_SELL + (size_t)MAXN_*4;          // MAXN*C float (aliased by CAND pre-gather)
constexpr size_t OFF_ANCH    = OFF_FEAT + (size_t)MAXN_*C_*4;
constexpr size_t OFF_KEYS    = OFF_ANCH + (size_t)MAXN_*C_*4;       // MAXN*2*C float
constexpr size_t OFF_PAF     = OFF_KEYS + (size_t)MAXN_*2*C_*4;
constexpr size_t OFF_PAM     = OFF_PAF + (size_t)MAXN_*4;
constexpr size_t OFF_LBASE   = OFF_PAM + (size_t)MAXN_*4;
constexpr size_t OFF_CURS    = OFF_LBASE + 512;
constexpr size_t OFF_PFP     = OFF_CURS + 512;                      // MAXN*NRF float4
constexpr size_t OFF_PMP     = OFF_PFP + (size_t)MAXN_*NRF_*16;     // MAXN*NRM float4
constexpr size_t OFF_END     = OFF_PMP + (size_t)MAXN_*NRM_*16;
constexpr size_t OFF_CAND    = OFF_FEAT;   // candidate keys alias FEAT region

__device__ __forceinline__ float bredSum(float v, float* red) {
    int t = threadIdx.x;
    red[t] = v; __syncthreads();
    for (int s = 128; s > 0; s >>= 1) { if (t < s) red[t] += red[t + s]; __syncthreads(); }
    float r = red[0]; __syncthreads();
    return r;
}

// ---------------- 1. softmax / argmax / histograms ----------------
__global__ void k_softmax_predict(const float* __restrict__ seg, const int* __restrict__ gt,
                                  int* __restrict__ predict, float* __restrict__ probc,
                                  int* __restrict__ cnt_all, int* __restrict__ cnt_easy) {
    __shared__ int h_all[B_*NCLS_];
    __shared__ int h_easy[B_*NCLS_];
    int t = threadIdx.x;
    if (t < B_*NCLS_) { h_all[t] = 0; h_easy[t] = 0; }
    __syncthreads();
    int idx = blockIdx.x * blockDim.x + t;
    if (idx < B_*N_) {
        int b = idx / N_, p = idx - b*N_;
        const float* base = seg + (size_t)b*NCLS_*N_ + p;
        float v[NCLS_];
        float mx = base[0]; v[0] = mx; int am = 0;
        for (int k = 1; k < NCLS_; ++k) {
            float x = base[(size_t)k*N_];
            v[k] = x;
            if (x > mx) { mx = x; am = k; }
        }
        float s = 0.f;
        for (int k = 0; k < NCLS_; ++k) s += expf(v[k] - mx);
        int lab = gt[idx];
        float pv = 0.f;
        if (lab >= 0 && lab < NCLS_) {
            pv = expf(v[lab] - mx) / s;
            atomicAdd(&h_all[b*NCLS_ + lab], 1);
            if (am == lab) atomicAdd(&h_easy[b*NCLS_ + lab], 1);
        }
        predict[idx] = am;
        probc[idx] = pv;
    }
    __syncthreads();
    if (t < B_*NCLS_) {
        if (h_all[t])  atomicAdd(&cnt_all[t],  h_all[t]);
        if (h_easy[t]) atomicAdd(&cnt_easy[t], h_easy[t]);
    }
}

// ---------------- 2. mining plan (single thread) ----------------
__global__ void k_plan(const int* __restrict__ cnt_all, const int* __restrict__ cnt_easy,
                       int* __restrict__ meta, int* __restrict__ pairs,
                       int* __restrict__ lbase, int* __restrict__ cursor) {
    if (threadIdx.x != 0 || blockIdx.x != 0) return;
    int total = 0;
    for (int i = 0; i < B_*NCLS_; ++i) if (cnt_all[i] > THRESH_) total++;
    meta[0] = total;
    int n_view = 0;
    if (total > 0) { n_view = MAXSAMP_ / total; if (n_view > THRESH_) n_view = THRESH_; }
    meta[1] = n_view;
    int off = 0;
    for (int i = 0; i < B_*NCLS_; ++i) {
        int q = (cnt_all[i] > THRESH_) ? 1 : 0;
        int h_take = 0, e_take = 0;
        if (q) {
            int ne = cnt_easy[i];
            int nh = cnt_all[i] - ne;
            int nhk, nek;
            bool hb = 2*nh >= n_view, eb = 2*ne >= n_view;
            if (hb && eb)      { nhk = n_view/2; nek = n_view - nhk; }
            else if (hb)       { nek = ne;       nhk = n_view - nek; }
            else if (eb)       { nhk = nh;       nek = n_view - nhk; }
            else               { nhk = nh;       nek = ne; }
            h_take = nhk < nh ? nhk : nh;
            e_take = nek < ne ? nek : ne;
        }
        pairs[4*i+0] = q; pairs[4*i+1] = h_take; pairs[4*i+2] = e_take; pairs[4*i+3] = off;
        off += h_take + e_take;
    }
    meta[2] = off;
    int run = 0;
    for (int i = 0; i < B_*NCLS_; ++i) {
        int ne = cnt_easy[i];
        int nh = cnt_all[i] - ne;
        lbase[2*i+0] = run; run += ne;   // easy list
        lbase[2*i+1] = run; run += nh;   // hard list
        cursor[2*i+0] = 0; cursor[2*i+1] = 0;
    }
}

// ---------------- 3a. compact candidates into per-list segments ----------------
__global__ void k_scatter(const int* __restrict__ gt, const int* __restrict__ predict,
                          const float* __restrict__ probc, const int* __restrict__ lbase,
                          int* __restrict__ cursor, unsigned long long* __restrict__ cand) {
    int idx = blockIdx.x * blockDim.x + threadIdx.x;
    if (idx >= B_*N_) return;
    int lab = gt[idx];
    if (lab < 0 || lab >= NCLS_) return;
    int b = idx / N_, p = idx - b*N_;
    int ishard = (predict[idx] != lab) ? 1 : 0;
    int L = (b*NCLS_ + lab)*2 + ishard;
    int pos = atomicAdd(&cursor[L], 1);
    unsigned int pb = __float_as_uint(probc[idx]);
    unsigned int lo = ishard ? (0xFFFFFFFFu - (unsigned int)p) : (unsigned int)p;
    cand[(size_t)lbase[L] + pos] = ((unsigned long long)pb << 32) | (unsigned long long)lo;
}

// ---------------- 3b. exact ordered top-k per list ----------------
__global__ void k_select2(const int* __restrict__ cnt_all, const int* __restrict__ cnt_easy,
                          const int* __restrict__ pairs, const int* __restrict__ lbase,
                          const unsigned long long* __restrict__ cand,
                          int* __restrict__ sel_b, int* __restrict__ sel_p, int* __restrict__ sel_l) {
    __shared__ unsigned long long s_key[256];
    __shared__ unsigned long long keys[CAP_];
    int bid = blockIdx.x;
    int slot = bid >> 1, ishard = bid & 1;
    if (!pairs[4*slot]) return;
    int h_take = pairs[4*slot+1], e_take = pairs[4*slot+2];
    int take = ishard ? h_take : e_take;
    if (take == 0) return;
    int off = pairs[4*slot+3] + (ishard ? 0 : h_take);
    int ne = cnt_easy[slot];
    int m = ishard ? (cnt_all[slot] - ne) : ne;
    int L = slot*2 + ishard;
    const unsigned long long* g = cand + lbase[L];
    int t = threadIdx.x;
    bool fits = (m <= CAP_);
    if (fits) {
        for (int j = t; j < m; j += 256) keys[j] = g[j];
        __syncthreads();
    }
    int b = slot / NCLS_, c = slot - b*NCLS_;
    unsigned long long prev = ishard ? 0xFFFFFFFFFFFFFFFFull : 0ull;
    for (int it = 0; it < take; ++it) {
        unsigned long long best = ishard ? 0ull : 0xFFFFFFFFFFFFFFFFull;
        if (ishard) {
            for (int j = t; j < m; j += 256) {
                unsigned long long k = fits ? keys[j] : g[j];
                if (k < prev && k > best) best = k;
            }
        } else {
            for (int j = t; j < m; j += 256) {
                unsigned long long k = fits ? keys[j] : g[j];
                if (k > prev && k < best) best = k;
            }
        }
        s_key[t] = best; __syncthreads();
        for (int s = 128; s > 0; s >>= 1) {
            if (t < s) {
                unsigned long long o = s_key[t+s];
                if (ishard ? (o > s_key[t]) : (o < s_key[t])) s_key[t] = o;
            }
            __syncthreads();
        }
        prev = s_key[0]; __syncthreads();
        if (t == 0) {
            unsigned int lo = (unsigned int)(prev & 0xFFFFFFFFull);
            int p = ishard ? (int)(0xFFFFFFFFu - lo) : (int)lo;
            sel_b[off+it] = b; sel_p[off+it] = p; sel_l[off+it] = c;
        }
    }
}

// ---------------- 4. gather + l2-normalize selected vectors ----------------
__global__ void k_gather(const float* __restrict__ pf, const float* __restrict__ pm,
                         const int* __restrict__ meta, const int* __restrict__ sel_b,
                         const int* __restrict__ sel_p,
                         float* __restrict__ sfeat, float* __restrict__ sanch, float* __restrict__ skeys) {
    __shared__ float red[256];
    int s = blockIdx.x;
    if (s >= meta[2]) return;
    int b = sel_b[s], p = sel_p[s];
    int t = threadIdx.x;  // == channel
    {
        float x = pf[((size_t)(b*C_ + t))*N_ + p];
        float ss = bredSum(x*x, red);
        sfeat[(size_t)s*C_ + t] = x / fmaxf(sqrtf(ss), 1e-12f);
    }
    {
        float x = pm[((size_t)((2*B_ + b)*C_ + t))*N_ + p];
        float ss = bredSum(x*x, red);
        sanch[(size_t)s*C_ + t] = x / fmaxf(sqrtf(ss), 1e-12f);
    }
    for (int j = 0; j < 2; ++j) {
        float x = pm[((size_t)((j*B_ + b)*C_ + t))*N_ + p];
        float ss = bredSum(x*x, red);
        skeys[((size_t)(2*s + j))*C_ + t] = x / fmaxf(sqrtf(ss), 1e-12f);
    }
}

// ---------------- 5. fused tiled GEMM + online masked-softmax partials ----------------
// MODE 0 (feat): keys = sfeat, M = n.  per-col: denom over col!=row (incl. positives);
//                pos-sum over same-label & col!=row.
// MODE 1 (mask): keys = [sanch | skeys], M = 3n. tot = same-label(qm) (& col!=row for col<n);
//                denom over !tot only.
// Emits per (row, key-range): {m_range, sum_neg exp(L-m), sum_tot L, count_tot}.
template<int MODE>
__global__ void k_rows_gemm(const int* __restrict__ meta, const float* __restrict__ Afeat,
                            const float* __restrict__ anch, const float* __restrict__ keysrc,
                            const int* __restrict__ sel_l, float4* __restrict__ part) {
    constexpr int AT  = MODE ? 128 : 64;
    constexpr int RPT = MODE ? 8 : 4;
    constexpr int NR  = MODE ? NRM_ : NRF_;
    const int n = meta[2];
    const int M = MODE ? 3*n : n;
    const int a0 = blockIdx.x * AT;
    const int r0 = blockIdx.y * 128;
    if (a0 >= n || r0 >= M) return;

    __shared__ float Als[AT][36];
    __shared__ float Bls[128][36];
    __shared__ int   sl[MAXN_];
    const int t = threadIdx.x;
    const int tx = t & 15, ty = t >> 4;
    for (int j = t; j < n; j += 256) sl[j] = sel_l[j];

    float acc[RPT][8];
    #pragma unroll
    for (int i = 0; i < RPT; ++i)
        #pragma unroll
        for (int j = 0; j < 8; ++j) acc[i][j] = 0.f;

    const float* Asrc = MODE ? anch : Afeat;

    for (int kk = 0; kk < C_; kk += 32) {
        __syncthreads();
        // stage A tile [AT][32] (row-major, pad 36)
        #pragma unroll
        for (int q = 0; q < AT/32; ++q) {
            int f = t + 256*q;
            int r = f >> 3, kq = f & 7;
            float4 v = make_float4(0.f,0.f,0.f,0.f);
            int gr = a0 + r;
            if (gr < n) v = *(const float4*)&Asrc[(size_t)gr*C_ + kk + kq*4];
            *(float4*)&Als[r][kq*4] = v;
        }
        // stage B tile [128][32]
        #pragma unroll
        for (int q = 0; q < 4; ++q) {
            int f = t + 256*q;
            int r = f >> 3, kq = f & 7;
            int gc = r0 + r;
            float4 v = make_float4(0.f,0.f,0.f,0.f);
            if (gc < M) {
                const float* src;
                if (MODE == 0) src = &Afeat[(size_t)gc*C_];
                else src = (gc < n) ? &anch[(size_t)gc*C_] : &keysrc[(size_t)(gc - n)*C_];
                v = *(const float4*)&src[kk + kq*4];
            }
            *(float4*)&Bls[r][kq*4] = v;
        }
        __syncthreads();
        #pragma unroll
        for (int kq = 0; kq < 8; ++kq) {
            const int k = kq*4;
            float4 av[RPT];
            #pragma unroll
            for (int i = 0; i < RPT; ++i) av[i] = *(const float4*)&Als[ty + 16*i][k];
            #pragma unroll
            for (int j = 0; j < 8; ++j) {
                float4 bv = *(const float4*)&Bls[tx + 16*j][k];
                #pragma unroll
                for (int i = 0; i < RPT; ++i) {
                    acc[i][j] = fmaf(av[i].x, bv.x, acc[i][j]);
                    acc[i][j] = fmaf(av[i].y, bv.y, acc[i][j]);
                    acc[i][j] = fmaf(av[i].z, bv.z, acc[i][j]);
                    acc[i][j] = fmaf(av[i].w, bv.w, acc[i][j]);
                }
            }
        }
    }

    // epilogue: per row, online-softmax partials over this key range
    const int ri = blockIdx.y;
    #pragma unroll
    for (int i = 0; i < RPT; ++i) {
        int row = a0 + ty + 16*i;
        if (row >= n) continue;          // uniform per 16-lane group
        int la = sl[row];
        float vals[8];
        float m = -INFINITY;
        #pragma unroll
        for (int j = 0; j < 8; ++j) {
            int col = r0 + tx + 16*j;
            float L = acc[i][j] * 10.0f;
            vals[j] = L;
            if (col < M) m = fmaxf(m, L);
        }
        #pragma unroll
        for (int d = 1; d < 16; d <<= 1) m = fmaxf(m, __shfl_xor(m, d, 16));
        float dn = 0.f, S = 0.f, cnt = 0.f;
        #pragma unroll
        for (int j = 0; j < 8; ++j) {
            int col = r0 + tx + 16*j;
            if (col >= M) continue;
            float L = vals[j];
            if (MODE == 0) {
                if (col != row) {
                    dn += expf(L - m);
                    if (sl[col] == la) { S += L; cnt += 1.f; }
                }
            } else {
                int q = col - n;
                int qm = (col < n) ? col : (q < n ? q : q - n);
                bool tot = (sl[qm] == la) && (col >= n || col != row);
                if (tot) { S += L; cnt += 1.f; }
                else dn += expf(L - m);
            }
        }
        #pragma unroll
        for (int d = 1; d < 16; d <<= 1) {
            dn  += __shfl_xor(dn, d, 16);
            S   += __shfl_xor(S, d, 16);
            cnt += __shfl_xor(cnt, d, 16);
        }
        if (tx == 0) part[(size_t)row*NR + ri] = make_float4(m, dn, S, cnt);
    }
}

// ---------------- 6. combine partials -> per-anchor losses ----------------
__global__ void k_combine(const int* __restrict__ meta, const float4* __restrict__ pfp,
                          const float4* __restrict__ pmp, float* __restrict__ paf,
                          float* __restrict__ pam) {
    int r = blockIdx.x*256 + threadIdx.x;
    int n = meta[2];
    if (r >= n) return;
    // feat
    {
        int nr = (n + 127) >> 7;
        float mg = -INFINITY;
        for (int i = 0; i < nr; ++i) mg = fmaxf(mg, pfp[(size_t)r*NRF_ + i].x);
        float dn = 0.f, S = 0.f, cnt = 0.f;
        for (int i = 0; i < nr; ++i) {
            float4 p = pfp[(size_t)r*NRF_ + i];
            dn += p.y * expf(p.x - mg);
            S += p.z; cnt += p.w;
        }
        float lg = logf(dn + 1e-16f);
        paf[r] = (S - cnt*mg - cnt*lg) / (cnt + 1e-16f);
    }
    // mask
    {
        int nr = (3*n + 127) >> 7;
        float mg = -INFINITY;
        for (int i = 0; i < nr; ++i) mg = fmaxf(mg, pmp[(size_t)r*NRM_ + i].x);
        float dn = 0.f, S = 0.f, cnt = 0.f;
        for (int i = 0; i < nr; ++i) {
            float4 p = pmp[(size_t)r*NRM_ + i];
            dn += p.y * expf(p.x - mg);
            S += p.z; cnt += p.w;
        }
        float lg = logf(dn + 1e-16f);
        pam[r] = (S - cnt*mg - cnt*lg) / (cnt + 1e-16f);
    }
}

// ---------------- 7. finalize ----------------
__global__ void k_final(const int* __restrict__ meta, const float* __restrict__ paf,
                        const float* __restrict__ pam, float* __restrict__ out) {
    __shared__ float red[256];
    int n = meta[2];
    int total = meta[0];
    int t = threadIdx.x;
    float sf = 0.f, sm = 0.f;
    for (int a = t; a < n; a += 256) { sf += paf[a]; sm += pam[a]; }
    sf = bredSum(sf, red);
    sm = bredSum(sm, red);
    if (t == 0) {
        if (total == 0 || n == 0) { out[0] = 0.f; out[1] = 0.f; }
        else {
            float scale = (float)(-(0.1/0.07));
            out[0] = scale * (sf / (float)n) * 0.1f;   // FEAT_W
            out[1] = scale * (sm / (float)n) * 0.1f;   // MASK_W
        }
    }
}

extern "C" void kernel_launch(void* const* d_in, const int* in_sizes, int n_in,
                              void* d_out, int out_size, void* d_ws, size_t ws_size,
                              hipStream_t stream) {
    const float* pf  = (const float*)d_in[0];   // proj_feats (B,C,H,W)
    const float* seg = (const float*)d_in[1];   // seg_logits (B,19,H,W)
    const int*   gt  = (const int*)d_in[2];     // groundtruth (B,1,H,W)
    const float* pm  = (const float*)d_in[3];   // proj_masks (3,B,256,H,W)
    float* out = (float*)d_out;
    char* ws = (char*)d_ws;

    int*   predict  = (int*)(ws + OFF_PREDICT);
    float* probc    = (float*)(ws + OFF_PROBC);
    int*   cnt_all  = (int*)(ws + OFF_CNT);
    int*   cnt_easy = cnt_all + B_*NCLS_;
    int*   meta     = (int*)(ws + OFF_META);
    int*   pairs    = (int*)(ws + OFF_PAIRS);
    int*   sel_b    = (int*)(ws + OFF_SELB);
    int*   sel_p    = (int*)(ws + OFF_SELP);
    int*   sel_l    = (int*)(ws + OFF_SELL);
    float* sfeat    = (float*)(ws + OFF_FEAT);
    float* sanch    = (float*)(ws + OFF_ANCH);
    float* skeys    = (float*)(ws + OFF_KEYS);
    float* paf      = (float*)(ws + OFF_PAF);
    float* pam      = (float*)(ws + OFF_PAM);
    int*   lbase    = (int*)(ws + OFF_LBASE);
    int*   cursor   = (int*)(ws + OFF_CURS);
    float4* pfp     = (float4*)(ws + OFF_PFP);
    float4* pmp     = (float4*)(ws + OFF_PMP);
    unsigned long long* cand = (unsigned long long*)(ws + OFF_CAND);

    hipMemsetAsync(ws + OFF_CNT, 0, 2*B_*NCLS_*sizeof(int), stream);

    k_softmax_predict<<<(B_*N_ + 255)/256, 256, 0, stream>>>(seg, gt, predict, probc, cnt_all, cnt_easy);
    k_plan<<<1, 1, 0, stream>>>(cnt_all, cnt_easy, meta, pairs, lbase, cursor);
    k_scatter<<<(B_*N_ + 255)/256, 256, 0, stream>>>(gt, predict, probc, lbase, cursor, cand);
    k_select2<<<NLIST_, 256, 0, stream>>>(cnt_all, cnt_easy, pairs, lbase, cand, sel_b, sel_p, sel_l);
    k_gather<<<MAXN_, 256, 0, stream>>>(pf, pm, meta, sel_b, sel_p, sfeat, sanch, skeys);
    k_rows_gemm<0><<<dim3(MAXN_/64, NRF_), 256, 0, stream>>>(meta, sfeat, sanch, skeys, sel_l, pfp);
    k_rows_gemm<1><<<dim3(MAXN_/128, NRM_), 256, 0, stream>>>(meta, sfeat, sanch, skeys, sel_l, pmp);
    k_combine<<<(MAXN_ + 255)/256, 256, 0, stream>>>(meta, pfp, pmp, paf, pam);
    k_final<<<1, 256, 0, stream>>>(meta, paf, pam, out);
}

// Round 4
// 288.233 us; speedup vs baseline: 5.0813x; 1.3522x over previous
//
#include <hip/hip_runtime.h>
#include <hip/hip_bf16.h>
#include <math.h>

#define B_ 2
#define NCLS_ 19
#define N_ 25600
#define C_ 256
#define MAXN_ 1024
#define THRESH_ 100
#define MAXSAMP_ 1024
#define NLIST_ (B_*NCLS_*2)
#define CAP_ 6144
#define NRF_ 8     // feat key ranges (MAXN/128)
#define NRM_ 24    // mask key ranges (3*MAXN/128)

// ---------------- workspace layout (bytes) ----------------
constexpr size_t OFF_PREDICT = 0;                                   // B*N int
constexpr size_t OFF_PROBC   = OFF_PREDICT + (size_t)B_*N_*4;       // B*N float
constexpr size_t OFF_CNT     = OFF_PROBC + (size_t)B_*N_*4;
constexpr size_t OFF_META    = OFF_CNT + 1024;
constexpr size_t OFF_PAIRS   = OFF_META + 256;
constexpr size_t OFF_SELB    = OFF_PAIRS + 1024;
constexpr size_t OFF_SELP    = OFF_SELB + (size_t)MAXN_*4;
constexpr size_t OFF_SELL    = OFF_SELP + (size_t)MAXN_*4;
constexpr size_t OFF_FEAT    = OFF_SELL + (size_t)MAXN_*4;          // MAXN*C float (aliased by CAND pre-gather)
constexpr size_t OFF_ANCH    = OFF_FEAT + (size_t)MAXN_*C_*4;
constexpr size_t OFF_KEYS    = OFF_ANCH + (size_t)MAXN_*C_*4;       // MAXN*2*C float
constexpr size_t OFF_PAF     = OFF_KEYS + (size_t)MAXN_*2*C_*4;
constexpr size_t OFF_PAM     = OFF_PAF + (size_t)MAXN_*4;
constexpr size_t OFF_LBASE   = OFF_PAM + (size_t)MAXN_*4;
constexpr size_t OFF_CURS    = OFF_LBASE + 512;
constexpr size_t OFF_PFP     = OFF_CURS + 512;                      // MAXN*NRF float4
constexpr size_t OFF_PMP     = OFF_PFP + (size_t)MAXN_*NRF_*16;     // MAXN*NRM float4
constexpr size_t OFF_END     = OFF_PMP + (size_t)MAXN_*NRM_*16;
constexpr size_t OFF_CAND    = OFF_FEAT;   // candidate keys alias FEAT region

__device__ __forceinline__ float bredSum(float v, float* red) {
    int t = threadIdx.x;
    red[t] = v; __syncthreads();
    for (int s = 128; s > 0; s >>= 1) { if (t < s) red[t] += red[t + s]; __syncthreads(); }
    float r = red[0]; __syncthreads();
    return r;
}

// ---------------- 1. softmax / argmax / histograms ----------------
__global__ void k_softmax_predict(const float* __restrict__ seg, const int* __restrict__ gt,
                                  int* __restrict__ predict, float* __restrict__ probc,
                                  int* __restrict__ cnt_all, int* __restrict__ cnt_easy) {
    __shared__ int h_all[B_*NCLS_];
    __shared__ int h_easy[B_*NCLS_];
    int t = threadIdx.x;
    if (t < B_*NCLS_) { h_all[t] = 0; h_easy[t] = 0; }
    __syncthreads();
    int idx = blockIdx.x * blockDim.x + t;
    if (idx < B_*N_) {
        int b = idx / N_, p = idx - b*N_;
        const float* base = seg + (size_t)b*NCLS_*N_ + p;
        float v[NCLS_];
        float mx = base[0]; v[0] = mx; int am = 0;
        for (int k = 1; k < NCLS_; ++k) {
            float x = base[(size_t)k*N_];
            v[k] = x;
            if (x > mx) { mx = x; am = k; }
        }
        float s = 0.f;
        for (int k = 0; k < NCLS_; ++k) s += expf(v[k] - mx);
        int lab = gt[idx];
        float pv = 0.f;
        if (lab >= 0 && lab < NCLS_) {
            pv = expf(v[lab] - mx) / s;
            atomicAdd(&h_all[b*NCLS_ + lab], 1);
            if (am == lab) atomicAdd(&h_easy[b*NCLS_ + lab], 1);
        }
        predict[idx] = am;
        probc[idx] = pv;
    }
    __syncthreads();
    if (t < B_*NCLS_) {
        if (h_all[t])  atomicAdd(&cnt_all[t],  h_all[t]);
        if (h_easy[t]) atomicAdd(&cnt_easy[t], h_easy[t]);
    }
}

// ---------------- 2. mining plan (single thread) ----------------
__global__ void k_plan(const int* __restrict__ cnt_all, const int* __restrict__ cnt_easy,
                       int* __restrict__ meta, int* __restrict__ pairs,
                       int* __restrict__ lbase, int* __restrict__ cursor) {
    if (threadIdx.x != 0 || blockIdx.x != 0) return;
    int total = 0;
    for (int i = 0; i < B_*NCLS_; ++i) if (cnt_all[i] > THRESH_) total++;
    meta[0] = total;
    int n_view = 0;
    if (total > 0) { n_view = MAXSAMP_ / total; if (n_view > THRESH_) n_view = THRESH_; }
    meta[1] = n_view;
    int off = 0;
    for (int i = 0; i < B_*NCLS_; ++i) {
        int q = (cnt_all[i] > THRESH_) ? 1 : 0;
        int h_take = 0, e_take = 0;
        if (q) {
            int ne = cnt_easy[i];
            int nh = cnt_all[i] - ne;
            int nhk, nek;
            bool hb = 2*nh >= n_view, eb = 2*ne >= n_view;
            if (hb && eb)      { nhk = n_view/2; nek = n_view - nhk; }
            else if (hb)       { nek = ne;       nhk = n_view - nek; }
            else if (eb)       { nhk = nh;       nek = n_view - nhk; }
            else               { nhk = nh;       nek = ne; }
            h_take = nhk < nh ? nhk : nh;
            e_take = nek < ne ? nek : ne;
        }
        pairs[4*i+0] = q; pairs[4*i+1] = h_take; pairs[4*i+2] = e_take; pairs[4*i+3] = off;
        off += h_take + e_take;
    }
    meta[2] = off;
    int run = 0;
    for (int i = 0; i < B_*NCLS_; ++i) {
        int ne = cnt_easy[i];
        int nh = cnt_all[i] - ne;
        lbase[2*i+0] = run; run += ne;   // easy list
        lbase[2*i+1] = run; run += nh;   // hard list
        cursor[2*i+0] = 0; cursor[2*i+1] = 0;
    }
}

// ---------------- 3a. compact candidates into per-list segments ----------------
__global__ void k_scatter(const int* __restrict__ gt, const int* __restrict__ predict,
                          const float* __restrict__ probc, const int* __restrict__ lbase,
                          int* __restrict__ cursor, unsigned long long* __restrict__ cand) {
    int idx = blockIdx.x * blockDim.x + threadIdx.x;
    if (idx >= B_*N_) return;
    int lab = gt[idx];
    if (lab < 0 || lab >= NCLS_) return;
    int b = idx / N_, p = idx - b*N_;
    int ishard = (predict[idx] != lab) ? 1 : 0;
    int L = (b*NCLS_ + lab)*2 + ishard;
    int pos = atomicAdd(&cursor[L], 1);
    unsigned int pb = __float_as_uint(probc[idx]);
    unsigned int lo = ishard ? (0xFFFFFFFFu - (unsigned int)p) : (unsigned int)p;
    cand[(size_t)lbase[L] + pos] = ((unsigned long long)pb << 32) | (unsigned long long)lo;
}

// ---------------- 3b. exact ordered top-k per list ----------------
__global__ void k_select2(const int* __restrict__ cnt_all, const int* __restrict__ cnt_easy,
                          const int* __restrict__ pairs, const int* __restrict__ lbase,
                          const unsigned long long* __restrict__ cand,
                          int* __restrict__ sel_b, int* __restrict__ sel_p, int* __restrict__ sel_l) {
    __shared__ unsigned long long s_key[256];
    __shared__ unsigned long long keys[CAP_];
    int bid = blockIdx.x;
    int slot = bid >> 1, ishard = bid & 1;
    if (!pairs[4*slot]) return;
    int h_take = pairs[4*slot+1], e_take = pairs[4*slot+2];
    int take = ishard ? h_take : e_take;
    if (take == 0) return;
    int off = pairs[4*slot+3] + (ishard ? 0 : h_take);
    int ne = cnt_easy[slot];
    int m = ishard ? (cnt_all[slot] - ne) : ne;
    int L = slot*2 + ishard;
    const unsigned long long* g = cand + lbase[L];
    int t = threadIdx.x;
    bool fits = (m <= CAP_);
    if (fits) {
        for (int j = t; j < m; j += 256) keys[j] = g[j];
        __syncthreads();
    }
    int b = slot / NCLS_, c = slot - b*NCLS_;
    unsigned long long prev = ishard ? 0xFFFFFFFFFFFFFFFFull : 0ull;
    for (int it = 0; it < take; ++it) {
        unsigned long long best = ishard ? 0ull : 0xFFFFFFFFFFFFFFFFull;
        if (ishard) {
            for (int j = t; j < m; j += 256) {
                unsigned long long k = fits ? keys[j] : g[j];
                if (k < prev && k > best) best = k;
            }
        } else {
            for (int j = t; j < m; j += 256) {
                unsigned long long k = fits ? keys[j] : g[j];
                if (k > prev && k < best) best = k;
            }
        }
        s_key[t] = best; __syncthreads();
        for (int s = 128; s > 0; s >>= 1) {
            if (t < s) {
                unsigned long long o = s_key[t+s];
                if (ishard ? (o > s_key[t]) : (o < s_key[t])) s_key[t] = o;
            }
            __syncthreads();
        }
        prev = s_key[0]; __syncthreads();
        if (t == 0) {
            unsigned int lo = (unsigned int)(prev & 0xFFFFFFFFull);
            int p = ishard ? (int)(0xFFFFFFFFu - lo) : (int)lo;
            sel_b[off+it] = b; sel_p[off+it] = p; sel_l[off+it] = c;
        }
    }
}

// ---------------- 4. gather + l2-normalize selected vectors ----------------
__global__ void k_gather(const float* __restrict__ pf, const float* __restrict__ pm,
                         const int* __restrict__ meta, const int* __restrict__ sel_b,
                         const int* __restrict__ sel_p,
                         float* __restrict__ sfeat, float* __restrict__ sanch, float* __restrict__ skeys) {
    __shared__ float red[256];
    int s = blockIdx.x;
    if (s >= meta[2]) return;
    int b = sel_b[s], p = sel_p[s];
    int t = threadIdx.x;  // == channel
    {
        float x = pf[((size_t)(b*C_ + t))*N_ + p];
        float ss = bredSum(x*x, red);
        sfeat[(size_t)s*C_ + t] = x / fmaxf(sqrtf(ss), 1e-12f);
    }
    {
        float x = pm[((size_t)((2*B_ + b)*C_ + t))*N_ + p];
        float ss = bredSum(x*x, red);
        sanch[(size_t)s*C_ + t] = x / fmaxf(sqrtf(ss), 1e-12f);
    }
    for (int j = 0; j < 2; ++j) {
        float x = pm[((size_t)((j*B_ + b)*C_ + t))*N_ + p];
        float ss = bredSum(x*x, red);
        skeys[((size_t)(2*s + j))*C_ + t] = x / fmaxf(sqrtf(ss), 1e-12f);
    }
}

// ---------------- 5. fused tiled GEMM + online masked-softmax partials ----------------
// MODE 0 (feat): keys = sfeat, M = n.  MODE 1 (mask): keys = [sanch | skeys], M = 3n.
// Emits per (row, key-range): {m_range, sum_neg exp(L-m), sum_tot L, count_tot}.
template<int MODE>
__global__ void __launch_bounds__(256, 2)
k_rows_gemm(const int* __restrict__ meta, const float* __restrict__ Afeat,
            const float* __restrict__ anch, const float* __restrict__ keysrc,
            const int* __restrict__ sel_l, float4* __restrict__ part) {
    constexpr int AT  = MODE ? 128 : 64;
    constexpr int RPT = MODE ? 8 : 4;
    constexpr int NR  = MODE ? NRM_ : NRF_;
    const int n = meta[2];
    const int M = MODE ? 3*n : n;
    const int a0 = blockIdx.x * AT;
    const int r0 = blockIdx.y * 128;
    if (a0 >= n || r0 >= M) return;

    __shared__ float Als[AT][36];
    __shared__ float Bls[128][36];
    __shared__ int   sl[MAXN_];
    const int t = threadIdx.x;
    const int tx = t & 15, ty = t >> 4;
    for (int j = t; j < n; j += 256) sl[j] = sel_l[j];

    float acc[RPT][8];
    #pragma unroll
    for (int i = 0; i < RPT; ++i)
        #pragma unroll
        for (int j = 0; j < 8; ++j) acc[i][j] = 0.f;

    const float* Asrc = MODE ? anch : Afeat;

    for (int kk = 0; kk < C_; kk += 32) {
        __syncthreads();
        // stage A tile [AT][32] (row-major, pad 36)
        #pragma unroll
        for (int q = 0; q < AT/32; ++q) {
            int f = t + 256*q;
            int r = f >> 3, kq = f & 7;
            float4 v = make_float4(0.f,0.f,0.f,0.f);
            int gr = a0 + r;
            if (gr < n) v = *(const float4*)&Asrc[(size_t)gr*C_ + kk + kq*4];
            *(float4*)&Als[r][kq*4] = v;
        }
        // stage B tile [128][32]
        #pragma unroll
        for (int q = 0; q < 4; ++q) {
            int f = t + 256*q;
            int r = f >> 3, kq = f & 7;
            int gc = r0 + r;
            float4 v = make_float4(0.f,0.f,0.f,0.f);
            if (gc < M) {
                const float* src;
                if (MODE == 0) src = &Afeat[(size_t)gc*C_];
                else src = (gc < n) ? &anch[(size_t)gc*C_] : &keysrc[(size_t)(gc - n)*C_];
                v = *(const float4*)&src[kk + kq*4];
            }
            *(float4*)&Bls[r][kq*4] = v;
        }
        __syncthreads();
        #pragma unroll
        for (int kq = 0; kq < 8; ++kq) {
            const int k = kq*4;
            float4 av[RPT];
            #pragma unroll
            for (int i = 0; i < RPT; ++i) av[i] = *(const float4*)&Als[ty + 16*i][k];
            #pragma unroll
            for (int j = 0; j < 8; ++j) {
                float4 bv = *(const float4*)&Bls[tx + 16*j][k];
                #pragma unroll
                for (int i = 0; i < RPT; ++i) {
                    acc[i][j] = fmaf(av[i].x, bv.x, acc[i][j]);
                    acc[i][j] = fmaf(av[i].y, bv.y, acc[i][j]);
                    acc[i][j] = fmaf(av[i].z, bv.z, acc[i][j]);
                    acc[i][j] = fmaf(av[i].w, bv.w, acc[i][j]);
                }
            }
        }
    }

    // epilogue: per row, online-softmax partials over this key range
    const int ri = blockIdx.y;
    #pragma unroll
    for (int i = 0; i < RPT; ++i) {
        int row = a0 + ty + 16*i;
        if (row >= n) continue;          // uniform per 16-lane group
        int la = sl[row];
        float vals[8];
        float m = -INFINITY;
        #pragma unroll
        for (int j = 0; j < 8; ++j) {
            int col = r0 + tx + 16*j;
            float L = acc[i][j] * 10.0f;
            vals[j] = L;
            if (col < M) m = fmaxf(m, L);
        }
        #pragma unroll
        for (int d = 1; d < 16; d <<= 1) m = fmaxf(m, __shfl_xor(m, d, 16));
        float dn = 0.f, S = 0.f, cnt = 0.f;
        #pragma unroll
        for (int j = 0; j < 8; ++j) {
            int col = r0 + tx + 16*j;
            if (col >= M) continue;
            float L = vals[j];
            if (MODE == 0) {
                if (col != row) {
                    dn += expf(L - m);
                    if (sl[col] == la) { S += L; cnt += 1.f; }
                }
            } else {
                int q = col - n;
                int qm = (col < n) ? col : (q < n ? q : q - n);
                bool tot = (sl[qm] == la) && (col >= n || col != row);
                if (tot) { S += L; cnt += 1.f; }
                else dn += expf(L - m);
            }
        }
        #pragma unroll
        for (int d = 1; d < 16; d <<= 1) {
            dn  += __shfl_xor(dn, d, 16);
            S   += __shfl_xor(S, d, 16);
            cnt += __shfl_xor(cnt, d, 16);
        }
        if (tx == 0) part[(size_t)row*NR + ri] = make_float4(m, dn, S, cnt);
    }
}

// ---------------- 6. combine partials -> per-anchor losses ----------------
__global__ void k_combine(const int* __restrict__ meta, const float4* __restrict__ pfp,
                          const float4* __restrict__ pmp, float* __restrict__ paf,
                          float* __restrict__ pam) {
    int r = blockIdx.x*256 + threadIdx.x;
    int n = meta[2];
    if (r >= n) return;
    // feat
    {
        int nr = (n + 127) >> 7;
        float mg = -INFINITY;
        for (int i = 0; i < nr; ++i) mg = fmaxf(mg, pfp[(size_t)r*NRF_ + i].x);
        float dn = 0.f, S = 0.f, cnt = 0.f;
        for (int i = 0; i < nr; ++i) {
            float4 p = pfp[(size_t)r*NRF_ + i];
            dn += p.y * expf(p.x - mg);
            S += p.z; cnt += p.w;
        }
        float lg = logf(dn + 1e-16f);
        paf[r] = (S - cnt*mg - cnt*lg) / (cnt + 1e-16f);
    }
    // mask
    {
        int nr = (3*n + 127) >> 7;
        float mg = -INFINITY;
        for (int i = 0; i < nr; ++i) mg = fmaxf(mg, pmp[(size_t)r*NRM_ + i].x);
        float dn = 0.f, S = 0.f, cnt = 0.f;
        for (int i = 0; i < nr; ++i) {
            float4 p = pmp[(size_t)r*NRM_ + i];
            dn += p.y * expf(p.x - mg);
            S += p.z; cnt += p.w;
        }
        float lg = logf(dn + 1e-16f);
        pam[r] = (S - cnt*mg - cnt*lg) / (cnt + 1e-16f);
    }
}

// ---------------- 7. finalize ----------------
__global__ void k_final(const int* __restrict__ meta, const float* __restrict__ paf,
                        const float* __restrict__ pam, float* __restrict__ out) {
    __shared__ float red[256];
    int n = meta[2];
    int total = meta[0];
    int t = threadIdx.x;
    float sf = 0.f, sm = 0.f;
    for (int a = t; a < n; a += 256) { sf += paf[a]; sm += pam[a]; }
    sf = bredSum(sf, red);
    sm = bredSum(sm, red);
    if (t == 0) {
        if (total == 0 || n == 0) { out[0] = 0.f; out[1] = 0.f; }
        else {
            float scale = (float)(-(0.1/0.07));
            out[0] = scale * (sf / (float)n) * 0.1f;   // FEAT_W
            out[1] = scale * (sm / (float)n) * 0.1f;   // MASK_W
        }
    }
}

extern "C" void kernel_launch(void* const* d_in, const int* in_sizes, int n_in,
                              void* d_out, int out_size, void* d_ws, size_t ws_size,
                              hipStream_t stream) {
    const float* pf  = (const float*)d_in[0];   // proj_feats (B,C,H,W)
    const float* seg = (const float*)d_in[1];   // seg_logits (B,19,H,W)
    const int*   gt  = (const int*)d_in[2];     // groundtruth (B,1,H,W)
    const float* pm  = (const float*)d_in[3];   // proj_masks (3,B,256,H,W)
    float* out = (float*)d_out;
    char* ws = (char*)d_ws;

    int*   predict  = (int*)(ws + OFF_PREDICT);
    float* probc    = (float*)(ws + OFF_PROBC);
    int*   cnt_all  = (int*)(ws + OFF_CNT);
    int*   cnt_easy = cnt_all + B_*NCLS_;
    int*   meta     = (int*)(ws + OFF_META);
    int*   pairs    = (int*)(ws + OFF_PAIRS);
    int*   sel_b    = (int*)(ws + OFF_SELB);
    int*   sel_p    = (int*)(ws + OFF_SELP);
    int*   sel_l    = (int*)(ws + OFF_SELL);
    float* sfeat    = (float*)(ws + OFF_FEAT);
    float* sanch    = (float*)(ws + OFF_ANCH);
    float* skeys    = (float*)(ws + OFF_KEYS);
    float* paf      = (float*)(ws + OFF_PAF);
    float* pam      = (float*)(ws + OFF_PAM);
    int*   lbase    = (int*)(ws + OFF_LBASE);
    int*   cursor   = (int*)(ws + OFF_CURS);
    float4* pfp     = (float4*)(ws + OFF_PFP);
    float4* pmp     = (float4*)(ws + OFF_PMP);
    unsigned long long* cand = (unsigned long long*)(ws + OFF_CAND);

    hipMemsetAsync(ws + OFF_CNT, 0, 2*B_*NCLS_*sizeof(int), stream);

    k_softmax_predict<<<(B_*N_ + 255)/256, 256, 0, stream>>>(seg, gt, predict, probc, cnt_all, cnt_easy);
    k_plan<<<1, 1, 0, stream>>>(cnt_all, cnt_easy, meta, pairs, lbase, cursor);
    k_scatter<<<(B_*N_ + 255)/256, 256, 0, stream>>>(gt, predict, probc, lbase, cursor, cand);
    k_select2<<<NLIST_, 256, 0, stream>>>(cnt_all, cnt_easy, pairs, lbase, cand, sel_b, sel_p, sel_l);
    k_gather<<<MAXN_, 256, 0, stream>>>(pf, pm, meta, sel_b, sel_p, sfeat, sanch, skeys);
    k_rows_gemm<0><<<dim3(MAXN_/64, NRF_), 256, 0, stream>>>(meta, sfeat, sanch, skeys, sel_l, pfp);
    k_rows_gemm<1><<<dim3(MAXN_/128, NRM_), 256, 0, stream>>>(meta, sfeat, sanch, skeys, sel_l, pmp);
    k_combine<<<(MAXN_ + 255)/256, 256, 0, stream>>>(meta, pfp, pmp, paf, pam);
    k_final<<<1, 256, 0, stream>>>(meta, paf, pam, out);
}

// Round 5
// 137.300 us; speedup vs baseline: 10.6672x; 2.0993x over previous
//
#include <hip/hip_runtime.h>
#include <hip/hip_bf16.h>
#include <math.h>

#define B_ 2
#define NCLS_ 19
#define N_ 25600
#define C_ 256
#define MAXN_ 1024
#define THRESH_ 100
#define MAXSAMP_ 1024
#define NLIST_ (B_*NCLS_*2)
#define CAP_ 6144
#define NRF_ 32    // feat key ranges (MAXN/32)
#define NRM_ 96    // mask key ranges (3*MAXN/32)

typedef __attribute__((ext_vector_type(8))) short bf16x8;
typedef __attribute__((ext_vector_type(4))) float f32x4;

// ---------------- workspace layout (bytes) ----------------
constexpr size_t OFF_PREDICT = 0;                                   // B*N int
constexpr size_t OFF_PROBC   = OFF_PREDICT + (size_t)B_*N_*4;       // B*N float
constexpr size_t OFF_CNT     = OFF_PROBC + (size_t)B_*N_*4;
constexpr size_t OFF_META    = OFF_CNT + 1024;
constexpr size_t OFF_PAIRS   = OFF_META + 256;
constexpr size_t OFF_SELB    = OFF_PAIRS + 1024;
constexpr size_t OFF_SELP    = OFF_SELB + (size_t)MAXN_*4;
constexpr size_t OFF_SELL    = OFF_SELP + (size_t)MAXN_*4;
constexpr size_t OFF_SFH     = OFF_SELL + (size_t)MAXN_*4;          // MAXN*C bf16 (aliased by CAND pre-gather)
constexpr size_t OFF_KMH     = OFF_SFH + (size_t)MAXN_*C_*2;        // 3*MAXN*C bf16
constexpr size_t OFF_PAF     = OFF_KMH + (size_t)3*MAXN_*C_*2;
constexpr size_t OFF_PAM     = OFF_PAF + (size_t)MAXN_*4;
constexpr size_t OFF_LBASE   = OFF_PAM + (size_t)MAXN_*4;
constexpr size_t OFF_CURS    = OFF_LBASE + 512;
constexpr size_t OFF_PFP     = OFF_CURS + 512;                      // MAXN*NRF float4
constexpr size_t OFF_PMP     = OFF_PFP + (size_t)MAXN_*NRF_*16;     // MAXN*NRM float4
constexpr size_t OFF_END     = OFF_PMP + (size_t)MAXN_*NRM_*16;
constexpr size_t OFF_CAND    = OFF_SFH;   // candidate keys (B*N u64 = 400KB <= 512KB SFH)

__device__ __forceinline__ float bredSum(float v, float* red) {
    int t = threadIdx.x;
    red[t] = v; __syncthreads();
    for (int s = 128; s > 0; s >>= 1) { if (t < s) red[t] += red[t + s]; __syncthreads(); }
    float r = red[0]; __syncthreads();
    return r;
}

__device__ __forceinline__ unsigned short f2bf(float x) {
    unsigned u = __float_as_uint(x);
    unsigned r = (u + 0x7FFFu + ((u >> 16) & 1u)) >> 16;   // RNE
    return (unsigned short)r;
}

// ---------------- 1. softmax / argmax / histograms ----------------
__global__ void k_softmax_predict(const float* __restrict__ seg, const int* __restrict__ gt,
                                  int* __restrict__ predict, float* __restrict__ probc,
                                  int* __restrict__ cnt_all, int* __restrict__ cnt_easy) {
    __shared__ int h_all[B_*NCLS_];
    __shared__ int h_easy[B_*NCLS_];
    int t = threadIdx.x;
    if (t < B_*NCLS_) { h_all[t] = 0; h_easy[t] = 0; }
    __syncthreads();
    int idx = blockIdx.x * blockDim.x + t;
    if (idx < B_*N_) {
        int b = idx / N_, p = idx - b*N_;
        const float* base = seg + (size_t)b*NCLS_*N_ + p;
        float v[NCLS_];
        float mx = base[0]; v[0] = mx; int am = 0;
        for (int k = 1; k < NCLS_; ++k) {
            float x = base[(size_t)k*N_];
            v[k] = x;
            if (x > mx) { mx = x; am = k; }
        }
        float s = 0.f;
        for (int k = 0; k < NCLS_; ++k) s += expf(v[k] - mx);
        int lab = gt[idx];
        float pv = 0.f;
        if (lab >= 0 && lab < NCLS_) {
            pv = expf(v[lab] - mx) / s;
            atomicAdd(&h_all[b*NCLS_ + lab], 1);
            if (am == lab) atomicAdd(&h_easy[b*NCLS_ + lab], 1);
        }
        predict[idx] = am;
        probc[idx] = pv;
    }
    __syncthreads();
    if (t < B_*NCLS_) {
        if (h_all[t])  atomicAdd(&cnt_all[t],  h_all[t]);
        if (h_easy[t]) atomicAdd(&cnt_easy[t], h_easy[t]);
    }
}

// ---------------- 2. mining plan (single thread) ----------------
__global__ void k_plan(const int* __restrict__ cnt_all, const int* __restrict__ cnt_easy,
                       int* __restrict__ meta, int* __restrict__ pairs,
                       int* __restrict__ lbase, int* __restrict__ cursor) {
    if (threadIdx.x != 0 || blockIdx.x != 0) return;
    int total = 0;
    for (int i = 0; i < B_*NCLS_; ++i) if (cnt_all[i] > THRESH_) total++;
    meta[0] = total;
    int n_view = 0;
    if (total > 0) { n_view = MAXSAMP_ / total; if (n_view > THRESH_) n_view = THRESH_; }
    meta[1] = n_view;
    int off = 0;
    for (int i = 0; i < B_*NCLS_; ++i) {
        int q = (cnt_all[i] > THRESH_) ? 1 : 0;
        int h_take = 0, e_take = 0;
        if (q) {
            int ne = cnt_easy[i];
            int nh = cnt_all[i] - ne;
            int nhk, nek;
            bool hb = 2*nh >= n_view, eb = 2*ne >= n_view;
            if (hb && eb)      { nhk = n_view/2; nek = n_view - nhk; }
            else if (hb)       { nek = ne;       nhk = n_view - nek; }
            else if (eb)       { nhk = nh;       nek = n_view - nhk; }
            else               { nhk = nh;       nek = ne; }
            h_take = nhk < nh ? nhk : nh;
            e_take = nek < ne ? nek : ne;
        }
        pairs[4*i+0] = q; pairs[4*i+1] = h_take; pairs[4*i+2] = e_take; pairs[4*i+3] = off;
        off += h_take + e_take;
    }
    meta[2] = off;
    int run = 0;
    for (int i = 0; i < B_*NCLS_; ++i) {
        int ne = cnt_easy[i];
        int nh = cnt_all[i] - ne;
        lbase[2*i+0] = run; run += ne;   // easy list
        lbase[2*i+1] = run; run += nh;   // hard list
        cursor[2*i+0] = 0; cursor[2*i+1] = 0;
    }
}

// ---------------- 3a. compact candidates (LDS-aggregated atomics) ----------------
__global__ void k_scatter(const int* __restrict__ gt, const int* __restrict__ predict,
                          const float* __restrict__ probc, const int* __restrict__ lbase,
                          int* __restrict__ cursor, unsigned long long* __restrict__ cand) {
    __shared__ int lcnt[NLIST_];
    __shared__ int lbeg[NLIST_];
    int t = threadIdx.x;
    if (t < NLIST_) lcnt[t] = 0;
    __syncthreads();
    int idx = blockIdx.x * blockDim.x + t;
    int L = -1, lp = 0;
    unsigned long long key = 0;
    if (idx < B_*N_) {
        int lab = gt[idx];
        if (lab >= 0 && lab < NCLS_) {
            int b = idx / N_, p = idx - b*N_;
            int ishard = (predict[idx] != lab) ? 1 : 0;
            L = (b*NCLS_ + lab)*2 + ishard;
            lp = atomicAdd(&lcnt[L], 1);
            unsigned int pb = __float_as_uint(probc[idx]);
            unsigned int lo = ishard ? (0xFFFFFFFFu - (unsigned int)p) : (unsigned int)p;
            key = ((unsigned long long)pb << 32) | (unsigned long long)lo;
        }
    }
    __syncthreads();
    if (t < NLIST_ && lcnt[t] > 0) lbeg[t] = atomicAdd(&cursor[t], lcnt[t]);
    __syncthreads();
    if (L >= 0) cand[(size_t)lbase[L] + lbeg[L] + lp] = key;
}

// ---------------- 3b. exact ordered top-k per list ----------------
__global__ void k_select2(const int* __restrict__ cnt_all, const int* __restrict__ cnt_easy,
                          const int* __restrict__ pairs, const int* __restrict__ lbase,
                          const unsigned long long* __restrict__ cand,
                          int* __restrict__ sel_b, int* __restrict__ sel_p, int* __restrict__ sel_l) {
    __shared__ unsigned long long s_key[256];
    __shared__ unsigned long long keys[CAP_];
    int bid = blockIdx.x;
    int slot = bid >> 1, ishard = bid & 1;
    if (!pairs[4*slot]) return;
    int h_take = pairs[4*slot+1], e_take = pairs[4*slot+2];
    int take = ishard ? h_take : e_take;
    if (take == 0) return;
    int off = pairs[4*slot+3] + (ishard ? 0 : h_take);
    int ne = cnt_easy[slot];
    int m = ishard ? (cnt_all[slot] - ne) : ne;
    int L = slot*2 + ishard;
    const unsigned long long* g = cand + lbase[L];
    int t = threadIdx.x;
    bool fits = (m <= CAP_);
    if (fits) {
        for (int j = t; j < m; j += 256) keys[j] = g[j];
        __syncthreads();
    }
    int b = slot / NCLS_, c = slot - b*NCLS_;
    unsigned long long prev = ishard ? 0xFFFFFFFFFFFFFFFFull : 0ull;
    for (int it = 0; it < take; ++it) {
        unsigned long long best = ishard ? 0ull : 0xFFFFFFFFFFFFFFFFull;
        if (ishard) {
            for (int j = t; j < m; j += 256) {
                unsigned long long k = fits ? keys[j] : g[j];
                if (k < prev && k > best) best = k;
            }
        } else {
            for (int j = t; j < m; j += 256) {
                unsigned long long k = fits ? keys[j] : g[j];
                if (k > prev && k < best) best = k;
            }
        }
        s_key[t] = best; __syncthreads();
        for (int s = 128; s > 0; s >>= 1) {
            if (t < s) {
                unsigned long long o = s_key[t+s];
                if (ishard ? (o > s_key[t]) : (o < s_key[t])) s_key[t] = o;
            }
            __syncthreads();
        }
        prev = s_key[0]; __syncthreads();
        if (t == 0) {
            unsigned int lo = (unsigned int)(prev & 0xFFFFFFFFull);
            int p = ishard ? (int)(0xFFFFFFFFu - lo) : (int)lo;
            sel_b[off+it] = b; sel_p[off+it] = p; sel_l[off+it] = c;
        }
    }
}

// ---------------- 4. gather + l2-normalize -> bf16 rows ----------------
// sfh[s]     : normalized feat row (for feat GEMM, A and B)
// km[s]      : normalized anchor row (rows 0..n-1)
// km[n+2s+j] : normalized key rows (j = 0,1)
__global__ void k_gather(const float* __restrict__ pf, const float* __restrict__ pm,
                         const int* __restrict__ meta, const int* __restrict__ sel_b,
                         const int* __restrict__ sel_p,
                         unsigned short* __restrict__ sfh, unsigned short* __restrict__ km) {
    __shared__ float red[256];
    int s = blockIdx.x;
    int n = meta[2];
    if (s >= n) return;
    int b = sel_b[s], p = sel_p[s];
    int t = threadIdx.x;  // == channel
    {
        float x = pf[((size_t)(b*C_ + t))*N_ + p];
        float ss = bredSum(x*x, red);
        sfh[(size_t)s*C_ + t] = f2bf(x / fmaxf(sqrtf(ss), 1e-12f));
    }
    {
        float x = pm[((size_t)((2*B_ + b)*C_ + t))*N_ + p];
        float ss = bredSum(x*x, red);
        km[(size_t)s*C_ + t] = f2bf(x / fmaxf(sqrtf(ss), 1e-12f));
    }
    for (int j = 0; j < 2; ++j) {
        float x = pm[((size_t)((j*B_ + b)*C_ + t))*N_ + p];
        float ss = bredSum(x*x, red);
        km[(size_t)(n + 2*s + j)*C_ + t] = f2bf(x / fmaxf(sqrtf(ss), 1e-12f));
    }
}

// ---------------- 5. fused MFMA GEMM + masked-softmax partials ----------------
// blockIdx.y < 16 : feat  (A=B=sfh, M=n,  part=pfp, NR=32)
// blockIdx.y >= 16: mask  (A=B=km,  M=3n, part=pmp, NR=96)
// Block = 64x64 tile, 4 waves in 2x2, each wave 32x32 via 2x2 mfma_f32_16x16x32_bf16.
// Partials per (row, 32-col range): {m, sum_neg exp(L-m), sum_tot L, count_tot}.
__global__ void __launch_bounds__(256, 4)
k_rows_mfma(const int* __restrict__ meta, const unsigned short* __restrict__ sfh,
            const unsigned short* __restrict__ km, const int* __restrict__ sel_l,
            float4* __restrict__ pfp, float4* __restrict__ pmp) {
    const int n = meta[2];
    const bool maskmode = (blockIdx.y >= 16);
    const int yb = maskmode ? (blockIdx.y - 16) : blockIdx.y;
    const int M = maskmode ? 3*n : n;
    const int rbase = blockIdx.x * 64;
    const int cbase = yb * 64;
    if (rbase >= n || cbase >= M) return;
    const unsigned short* buf = maskmode ? km : sfh;
    float4* part = maskmode ? pmp : pfp;
    const int NR = maskmode ? NRM_ : NRF_;

    __shared__ int sl[MAXN_];
    const int t = threadIdx.x;
    for (int j = t; j < n; j += 256) sl[j] = sel_l[j];
    __syncthreads();

    const int wid = t >> 6, lane = t & 63;
    const int wr = wid >> 1, wc = wid & 1;
    const int r0 = rbase + wr*32;
    const int c0 = cbase + wc*32;
    const int lrow = lane & 15, lk = (lane >> 4) * 8;

    const bf16x8 zero8 = {0,0,0,0,0,0,0,0};
    f32x4 acc[2][2];
    #pragma unroll
    for (int i = 0; i < 2; ++i)
        #pragma unroll
        for (int j = 0; j < 2; ++j) acc[i][j] = (f32x4){0.f,0.f,0.f,0.f};

    for (int kk = 0; kk < C_; kk += 32) {
        bf16x8 af[2], bfr[2];
        #pragma unroll
        for (int i = 0; i < 2; ++i) {
            int r = r0 + i*16 + lrow;
            af[i] = (r < n) ? *(const bf16x8*)&buf[(size_t)r*C_ + kk + lk] : zero8;
        }
        #pragma unroll
        for (int j = 0; j < 2; ++j) {
            int c = c0 + j*16 + lrow;
            bfr[j] = (c < M) ? *(const bf16x8*)&buf[(size_t)c*C_ + kk + lk] : zero8;
        }
        #pragma unroll
        for (int i = 0; i < 2; ++i)
            #pragma unroll
            for (int j = 0; j < 2; ++j)
                acc[i][j] = __builtin_amdgcn_mfma_f32_16x16x32_bf16(af[i], bfr[j], acc[i][j], 0, 0, 0);
    }

    // epilogue: C[r][c] layout: col = lane&15 (+j*16), row = (lane>>4)*4 + reg (+i*16)
    const int ri = yb*2 + wc;
    const int g4 = (lane >> 4) * 4;
    const int lc = lane & 15;
    #pragma unroll
    for (int i = 0; i < 2; ++i) {
        #pragma unroll
        for (int q = 0; q < 4; ++q) {
            int row = r0 + i*16 + g4 + q;
            bool rok = (row < n);
            int la = rok ? sl[row] : 0;
            float v0 = acc[i][0][q] * 10.0f;
            float v1 = acc[i][1][q] * 10.0f;
            int col0 = c0 + lc, col1 = c0 + 16 + lc;
            float m = -INFINITY;
            if (col0 < M) m = v0;
            if (col1 < M) m = fmaxf(m, v1);
            #pragma unroll
            for (int d = 1; d < 16; d <<= 1) m = fmaxf(m, __shfl_xor(m, d, 16));
            float dn = 0.f, S = 0.f, cnt = 0.f;
            #pragma unroll
            for (int jj = 0; jj < 2; ++jj) {
                int col = jj ? col1 : col0;
                float L = jj ? v1 : v0;
                if (col >= M) continue;
                if (!maskmode) {
                    if (col != row) {
                        dn += expf(L - m);
                        if (sl[col] == la) { S += L; cnt += 1.f; }
                    }
                } else {
                    int qq = col - n;
                    int qm = (col < n) ? col : (qq < n ? qq : qq - n);
                    bool tot = (sl[qm] == la) && (col >= n || col != row);
                    if (tot) { S += L; cnt += 1.f; }
                    else dn += expf(L - m);
                }
            }
            #pragma unroll
            for (int d = 1; d < 16; d <<= 1) {
                dn  += __shfl_xor(dn, d, 16);
                S   += __shfl_xor(S, d, 16);
                cnt += __shfl_xor(cnt, d, 16);
            }
            if (rok && lc == 0) part[(size_t)row*NR + ri] = make_float4(m, dn, S, cnt);
        }
    }
}

// ---------------- 6. combine partials -> per-anchor losses ----------------
__global__ void k_combine(const int* __restrict__ meta, const float4* __restrict__ pfp,
                          const float4* __restrict__ pmp, float* __restrict__ paf,
                          float* __restrict__ pam) {
    int r = blockIdx.x*256 + threadIdx.x;
    int n = meta[2];
    if (r >= n) return;
    // feat
    {
        int nr = (n + 31) >> 5;
        float mg = -INFINITY;
        for (int i = 0; i < nr; ++i) mg = fmaxf(mg, pfp[(size_t)r*NRF_ + i].x);
        float dn = 0.f, S = 0.f, cnt = 0.f;
        for (int i = 0; i < nr; ++i) {
            float4 p = pfp[(size_t)r*NRF_ + i];
            dn += p.y * expf(p.x - mg);
            S += p.z; cnt += p.w;
        }
        float lg = logf(dn + 1e-16f);
        paf[r] = (S - cnt*mg - cnt*lg) / (cnt + 1e-16f);
    }
    // mask
    {
        int nr = (3*n + 31) >> 5;
        float mg = -INFINITY;
        for (int i = 0; i < nr; ++i) mg = fmaxf(mg, pmp[(size_t)r*NRM_ + i].x);
        float dn = 0.f, S = 0.f, cnt = 0.f;
        for (int i = 0; i < nr; ++i) {
            float4 p = pmp[(size_t)r*NRM_ + i];
            dn += p.y * expf(p.x - mg);
            S += p.z; cnt += p.w;
        }
        float lg = logf(dn + 1e-16f);
        pam[r] = (S - cnt*mg - cnt*lg) / (cnt + 1e-16f);
    }
}

// ---------------- 7. finalize ----------------
__global__ void k_final(const int* __restrict__ meta, const float* __restrict__ paf,
                        const float* __restrict__ pam, float* __restrict__ out) {
    __shared__ float red[256];
    int n = meta[2];
    int total = meta[0];
    int t = threadIdx.x;
    float sf = 0.f, sm = 0.f;
    for (int a = t; a < n; a += 256) { sf += paf[a]; sm += pam[a]; }
    sf = bredSum(sf, red);
    sm = bredSum(sm, red);
    if (t == 0) {
        if (total == 0 || n == 0) { out[0] = 0.f; out[1] = 0.f; }
        else {
            float scale = (float)(-(0.1/0.07));
            out[0] = scale * (sf / (float)n) * 0.1f;   // FEAT_W
            out[1] = scale * (sm / (float)n) * 0.1f;   // MASK_W
        }
    }
}

extern "C" void kernel_launch(void* const* d_in, const int* in_sizes, int n_in,
                              void* d_out, int out_size, void* d_ws, size_t ws_size,
                              hipStream_t stream) {
    const float* pf  = (const float*)d_in[0];   // proj_feats (B,C,H,W)
    const float* seg = (const float*)d_in[1];   // seg_logits (B,19,H,W)
    const int*   gt  = (const int*)d_in[2];     // groundtruth (B,1,H,W)
    const float* pm  = (const float*)d_in[3];   // proj_masks (3,B,256,H,W)
    float* out = (float*)d_out;
    char* ws = (char*)d_ws;

    int*   predict  = (int*)(ws + OFF_PREDICT);
    float* probc    = (float*)(ws + OFF_PROBC);
    int*   cnt_all  = (int*)(ws + OFF_CNT);
    int*   cnt_easy = cnt_all + B_*NCLS_;
    int*   meta     = (int*)(ws + OFF_META);
    int*   pairs    = (int*)(ws + OFF_PAIRS);
    int*   sel_b    = (int*)(ws + OFF_SELB);
    int*   sel_p    = (int*)(ws + OFF_SELP);
    int*   sel_l    = (int*)(ws + OFF_SELL);
    unsigned short* sfh = (unsigned short*)(ws + OFF_SFH);
    unsigned short* km  = (unsigned short*)(ws + OFF_KMH);
    float* paf      = (float*)(ws + OFF_PAF);
    float* pam      = (float*)(ws + OFF_PAM);
    int*   lbase    = (int*)(ws + OFF_LBASE);
    int*   cursor   = (int*)(ws + OFF_CURS);
    float4* pfp     = (float4*)(ws + OFF_PFP);
    float4* pmp     = (float4*)(ws + OFF_PMP);
    unsigned long long* cand = (unsigned long long*)(ws + OFF_CAND);

    hipMemsetAsync(ws + OFF_CNT, 0, 2*B_*NCLS_*sizeof(int), stream);

    k_softmax_predict<<<(B_*N_ + 255)/256, 256, 0, stream>>>(seg, gt, predict, probc, cnt_all, cnt_easy);
    k_plan<<<1, 1, 0, stream>>>(cnt_all, cnt_easy, meta, pairs, lbase, cursor);
    k_scatter<<<(B_*N_ + 255)/256, 256, 0, stream>>>(gt, predict, probc, lbase, cursor, cand);
    k_select2<<<NLIST_, 256, 0, stream>>>(cnt_all, cnt_easy, pairs, lbase, cand, sel_b, sel_p, sel_l);
    k_gather<<<MAXN_, 256, 0, stream>>>(pf, pm, meta, sel_b, sel_p, sfh, km);
    k_rows_mfma<<<dim3(MAXN_/64, 64), 256, 0, stream>>>(meta, sfh, km, sel_l, pfp, pmp);
    k_combine<<<(MAXN_ + 255)/256, 256, 0, stream>>>(meta, pfp, pmp, paf, pam);
    k_final<<<1, 256, 0, stream>>>(meta, paf, pam, out);
}